// Round 1
// baseline (4759.494 us; speedup 1.0000x reference)
//
#include <hip/hip_runtime.h>
#include <math.h>

#define NB 2
#define NS 2048
#define ND 512
#define NH 8
#define NHD 64
#define NL 8
#define NFF 2048
#define NM (NB*NS)      // 4096 rows
#define NE 1248
#define CHK 64
#define NCH (NS/CHK)    // 32 chunks

// ---------------------------------------------------------------- tables
__global__ void k_tables(float* rc, float* rs, float* pe){
  int tid = blockIdx.x*blockDim.x + threadIdx.x;
  if (tid < NS*32){
    int s = tid >> 5, j = tid & 31;
    double inv = exp(-(double)(2*j) * log(10000.0) / (double)NHD);
    double ang = (double)s * inv;
    rc[tid] = (float)cos(ang);
    rs[tid] = (float)sin(ang);
  }
  if (tid < ND/2){
    double div = exp(-(double)(2*tid) * log(10000.0) / (double)ND);
    double ang = (double)NS * div;
    pe[2*tid]   = (float)sin(ang);
    pe[2*tid+1] = (float)cos(ang);
  }
}

// ---------------------------------------------------------------- embedding gather+concat (scaled)
__global__ void k_embed(const int* __restrict__ inp,
    const float* __restrict__ e0, const float* __restrict__ e1, const float* __restrict__ e2,
    const float* __restrict__ e3, const float* __restrict__ e4, const float* __restrict__ e5,
    const float* __restrict__ e6, float* __restrict__ xe)
{
  int row = blockIdx.x;
  int i0 = inp[row*7+0], i1 = inp[row*7+1], i2 = inp[row*7+2], i3 = inp[row*7+3],
      i4 = inp[row*7+4], i5 = inp[row*7+5], i6 = inp[row*7+6];
  size_t base = (size_t)row*NE;
  for (int c = threadIdx.x; c < NE; c += 256){
    float val;
    if      (c < 128)  val = e0[i0*128 + c]        * 11.3137084990f;
    else if (c < 384)  val = e1[i1*256 + (c-128)]  * 16.0f;
    else if (c < 448)  val = e2[i2*64  + (c-384)]  * 8.0f;
    else if (c < 480)  val = e3[i3*32  + (c-448)]  * 5.6568542495f;
    else if (c < 992)  val = e4[i4*512 + (c-480)]  * 22.6274169980f;
    else if (c < 1120) val = e5[i5*128 + (c-992)]  * 11.3137084990f;
    else               val = e6[i6*128 + (c-1120)] * 11.3137084990f;
    xe[base + c] = val;
  }
}

// ---------------------------------------------------------------- generic tiled fp32 GEMM
// C[r, ccol] = act(sum_k A[r,k]*B[k,ccol] + bias[ccol]) * scale ; C has leading dim ldc
__device__ inline float gelu_exact(float x){
  return 0.5f*x*(1.0f + erff(x*0.70710678118654752f));
}

__global__ __launch_bounds__(256) void k_gemm(const float* __restrict__ A, const float* __restrict__ Bw,
    const float* __restrict__ bias, float* __restrict__ C,
    int Mx, int N, int K, int ldc, float scale, int act)
{
  __shared__ float As[16][68];
  __shared__ float Bs[16][68];
  int tid = threadIdx.x;
  int tx = tid & 15, ty = tid >> 4;
  int m0 = blockIdx.y * 64, n0 = blockIdx.x * 64;
  int arow  = tid >> 2;
  int acol4 = (tid & 3) << 2;
  int brow  = tid >> 4;
  int bcol4 = (tid & 15) << 2;
  float acc[4][4];
  #pragma unroll
  for (int i=0;i<4;i++)
    #pragma unroll
    for (int j=0;j<4;j++) acc[i][j]=0.f;

  for (int k0 = 0; k0 < K; k0 += 16){
    float4 av = *(const float4*)(A + (size_t)(m0+arow)*K + k0 + acol4);
    As[acol4+0][arow]=av.x; As[acol4+1][arow]=av.y; As[acol4+2][arow]=av.z; As[acol4+3][arow]=av.w;
    float4 bv;
    int bc = n0 + bcol4;
    if (((N & 3) == 0) && bc < N){
      bv = *(const float4*)(Bw + (size_t)(k0+brow)*N + bc);
    } else {
      const float* bp = Bw + (size_t)(k0+brow)*N;
      bv.x = (bc+0<N)?bp[bc+0]:0.f; bv.y = (bc+1<N)?bp[bc+1]:0.f;
      bv.z = (bc+2<N)?bp[bc+2]:0.f; bv.w = (bc+3<N)?bp[bc+3]:0.f;
    }
    *(float4*)&Bs[brow][bcol4] = bv;
    __syncthreads();
    #pragma unroll
    for (int kk=0; kk<16; kk++){
      float a0=As[kk][ty*4+0], a1=As[kk][ty*4+1], a2=As[kk][ty*4+2], a3=As[kk][ty*4+3];
      float b0=Bs[kk][tx*4+0], b1=Bs[kk][tx*4+1], b2=Bs[kk][tx*4+2], b3=Bs[kk][tx*4+3];
      acc[0][0]+=a0*b0; acc[0][1]+=a0*b1; acc[0][2]+=a0*b2; acc[0][3]+=a0*b3;
      acc[1][0]+=a1*b0; acc[1][1]+=a1*b1; acc[1][2]+=a1*b2; acc[1][3]+=a1*b3;
      acc[2][0]+=a2*b0; acc[2][1]+=a2*b1; acc[2][2]+=a2*b2; acc[2][3]+=a2*b3;
      acc[3][0]+=a3*b0; acc[3][1]+=a3*b1; acc[3][2]+=a3*b2; acc[3][3]+=a3*b3;
    }
    __syncthreads();
  }
  #pragma unroll
  for (int i=0;i<4;i++){
    int r = m0 + ty*4 + i;
    #pragma unroll
    for (int j=0;j<4;j++){
      int ccol = n0 + tx*4 + j;
      if (ccol < N){
        float v = acc[i][j] + (bias ? bias[ccol] : 0.f);
        if (act == 1) v = gelu_exact(v);
        C[(size_t)r*ldc + ccol] = v * scale;
      }
    }
  }
}

// ---------------------------------------------------------------- x += pe (broadcast row)
__global__ void k_addpe(float* __restrict__ x, const float* __restrict__ pe){
  int row = blockIdx.x, tid = threadIdx.x;
  size_t base = (size_t)row*ND;
  x[base+tid]     += pe[tid];
  x[base+tid+256] += pe[tid+256];
}

// ---------------------------------------------------------------- RoPE + phi (elu+1), in-place on q and k
__global__ void k_ropephi(float* __restrict__ q, float* __restrict__ kb,
                          const float* __restrict__ rc, const float* __restrict__ rs){
  int idx = blockIdx.x*256 + threadIdx.x;      // over NM*256 pairs
  int row = idx >> 8;
  int p = idx & 255;
  int h = p >> 5, j = p & 31;
  int s = row & (NS-1);
  float c = rc[s*32+j], sn = rs[s*32+j];
  size_t i1 = (size_t)row*ND + h*NHD + j, i2 = i1 + 32;
  float q1=q[i1], q2=q[i2];
  float r1 = q1*c - q2*sn, r2 = q2*c + q1*sn;
  q[i1] = (r1 > 0.f) ? r1+1.f : expf(r1);
  q[i2] = (r2 > 0.f) ? r2+1.f : expf(r2);
  float k1=kb[i1], k2=kb[i2];
  r1 = k1*c - k2*sn; r2 = k2*c + k1*sn;
  kb[i1] = (r1 > 0.f) ? r1+1.f : expf(r1);
  kb[i2] = (r2 > 0.f) ? r2+1.f : expf(r2);
}

// ---------------------------------------------------------------- attention phase 1: per-chunk KV outer-sum + K sum
__global__ __launch_bounds__(256) void k_att1(const float* __restrict__ kb, const float* __restrict__ v,
    float* __restrict__ ckv, float* __restrict__ cks)
{
  int c = blockIdx.x, h = blockIdx.y, b = blockIdx.z;
  __shared__ float Ks[CHK][NHD];
  __shared__ float Vs[CHK][NHD];
  int tid = threadIdx.x;
  for (int e = tid; e < CHK*NHD; e += 256){
    int t = e >> 6, d = e & 63;
    size_t g = ((size_t)(b*NS + c*CHK + t))*ND + h*NHD + d;
    Ks[t][d] = kb[g]; Vs[t][d] = v[g];
  }
  __syncthreads();
  size_t obase = ((size_t)(b*NH + h))*NCH + c;
  #pragma unroll
  for (int i2 = 0; i2 < 16; i2++){
    int e = tid + i2*256;
    int m = e >> 6, dd = e & 63;
    float s = 0.f;
    #pragma unroll 8
    for (int t = 0; t < 64; t++) s += Ks[t][m]*Vs[t][dd];
    ckv[obase*4096 + e] = s;
  }
  if (tid < 64){
    float s = 0.f;
    #pragma unroll 8
    for (int t = 0; t < 64; t++) s += Ks[t][tid];
    cks[obase*64 + tid] = s;
  }
}

// ---------------------------------------------------------------- attention phase 2: exclusive prefix over chunks
__global__ __launch_bounds__(256) void k_att2(const float* __restrict__ ckv, const float* __restrict__ cks,
    float* __restrict__ pkv, float* __restrict__ pks)
{
  int bh = blockIdx.x; int tid = threadIdx.x;
  float run[16];
  #pragma unroll
  for (int i=0;i<16;i++) run[i]=0.f;
  float runk = 0.f;
  for (int c = 0; c < NCH; c++){
    size_t base = ((size_t)bh*NCH + c)*4096;
    #pragma unroll
    for (int i=0;i<16;i++){
      int e = tid + i*256;
      pkv[base+e] = run[i];
      run[i] += ckv[base+e];
    }
    if (tid < 64){
      size_t kbp = ((size_t)bh*NCH + c)*64 + tid;
      pks[kbp] = runk;
      runk += cks[kbp];
    }
  }
}

// ---------------------------------------------------------------- attention phase 3: in-chunk triangular part + output
__global__ __launch_bounds__(256) void k_att3(const float* __restrict__ q, const float* __restrict__ kb,
    const float* __restrict__ v, const float* __restrict__ pkv, const float* __restrict__ pks,
    float* __restrict__ outa)
{
  int c = blockIdx.x, h = blockIdx.y, b = blockIdx.z;
  __shared__ float Ks[CHK][NHD+1];   // padded: lane-indexed row reads
  __shared__ float Qs[CHK][NHD];
  __shared__ float Vs[CHK][NHD];
  int tid = threadIdx.x;
  for (int e = tid; e < CHK*NHD; e += 256){
    int t = e >> 6, d = e & 63;
    size_t g = ((size_t)(b*NS + c*CHK + t))*ND + h*NHD + d;
    Ks[t][d] = kb[g]; Qs[t][d] = q[g]; Vs[t][d] = v[g];
  }
  __syncthreads();
  int lane = tid & 63, w = tid >> 6;
  const float* pkvc = pkv + (((size_t)(b*NH + h))*NCH + c)*4096;
  const float* pksc = pks + (((size_t)(b*NH + h))*NCH + c)*64;
  for (int ii = 0; ii < 16; ii++){
    int i = w*16 + ii;
    float sc = 0.f;
    if (lane <= i){
      #pragma unroll 8
      for (int m = 0; m < 64; m++) sc += Qs[i][m]*Ks[lane][m];
    }
    float accv = 0.f, dacc = 0.f;
    #pragma unroll 4
    for (int m = 0; m < 64; m++){
      float qm = Qs[i][m];
      accv += qm * pkvc[m*64 + lane];
      dacc += qm * pksc[m];
    }
    float rowsum = 0.f;
    for (int t2 = 0; t2 < 64; t2++){
      float s_t = __shfl(sc, t2, 64);
      accv += s_t * Vs[t2][lane];
      rowsum += s_t;
    }
    float z = 1.0f / (dacc + rowsum + 1e-6f);
    outa[((size_t)(b*NS + c*CHK + i))*ND + h*NHD + lane] = accv * z;
  }
}

// ---------------------------------------------------------------- layernorm (optional residual), in-place safe
__global__ __launch_bounds__(256) void k_ln(const float* __restrict__ xin, const float* __restrict__ res,
    float* __restrict__ outx, const float* __restrict__ g, const float* __restrict__ bvec)
{
  int row = blockIdx.x, tid = threadIdx.x;
  size_t base = (size_t)row*ND;
  float v0 = xin[base+tid], v1 = xin[base+tid+256];
  if (res){ v0 += res[base+tid]; v1 += res[base+tid+256]; }
  float s = v0+v1, ss2 = v0*v0 + v1*v1;
  #pragma unroll
  for (int o = 32; o >= 1; o >>= 1){
    s   += __shfl_down(s, o, 64);
    ss2 += __shfl_down(ss2, o, 64);
  }
  __shared__ float red[8];
  int wv = tid >> 6, ln = tid & 63;
  if (ln == 0){ red[wv] = s; red[4+wv] = ss2; }
  __syncthreads();
  float stot  = red[0]+red[1]+red[2]+red[3];
  float sstot = red[4]+red[5]+red[6]+red[7];
  float mean = stot * (1.0f/ND);
  float var  = sstot * (1.0f/ND) - mean*mean;
  float inv = 1.0f / sqrtf(var + 1e-5f);
  outx[base+tid]     = (v0-mean)*inv*g[tid]     + bvec[tid];
  outx[base+tid+256] = (v1-mean)*inv*g[tid+256] + bvec[tid+256];
}

// ---------------------------------------------------------------- build xc_in = [x | emb_type(target)*sqrt(32)]
__global__ void k_xc(const float* __restrict__ x, const int* __restrict__ tgt,
                     const float* __restrict__ embt, float* __restrict__ xc){
  int row = blockIdx.x;
  int id = tgt[row*7+3];
  size_t base = (size_t)row*544;
  for (int c = threadIdx.x; c < 544; c += 256){
    xc[base+c] = (c < 512) ? x[(size_t)row*ND + c] : embt[id*32 + (c-512)]*5.6568542495f;
  }
}

// ---------------------------------------------------------------- pack all head weights (pre-scaled) into [512,343]
__global__ void k_pack(const float* p0,const float* p1,const float* p2,const float* p3,
                       const float* p4,const float* p5,const float* p6,
                       const float* q0,const float* q1,const float* q2,const float* q3,
                       const float* q4,const float* q5,const float* q6,
                       float* __restrict__ pwc, float* __restrict__ pbc){
  int idx = blockIdx.x*256 + threadIdx.x;
  const int off[8] = {0,56,191,209,213,300,318,343};
  if (idx < 512*343){
    int kk = idx / 343, col = idx % 343;
    int f = 0;
    while (col >= off[f+1]) f++;
    int cc = col - off[f];
    int V = off[f+1]-off[f];
    const float* P = (f==0)?p0:(f==1)?p1:(f==2)?p2:(f==3)?p3:(f==4)?p4:(f==5)?p5:p6;
    pwc[idx] = P[kk*V + cc] * sqrtf((float)V);
  }
  if (idx < 343){
    int col = idx; int f = 0;
    while (col >= off[f+1]) f++;
    int cc = col - off[f]; int V = off[f+1]-off[f];
    const float* Q = (f==0)?q0:(f==1)?q1:(f==2)?q2:(f==3)?q3:(f==4)?q4:(f==5)?q5:q6;
    pbc[idx] = Q[cc]*sqrtf((float)V);
  }
}

// ================================================================ host
extern "C" void kernel_launch(void* const* d_in, const int* in_sizes, int n_in,
                              void* d_out, int out_size, void* d_ws, size_t ws_size,
                              hipStream_t stream)
{
  const int* inputs = (const int*)d_in[0];
  const int* target = (const int*)d_in[1];
  const float* emb[7];
  for (int i=0;i<7;i++) emb[i] = (const float*)d_in[2+i];
  const float* in_W  = (const float*)d_in[9];
  const float* in_b  = (const float*)d_in[10];
  const float* Wq = (const float*)d_in[11];
  const float* Wk = (const float*)d_in[12];
  const float* Wv = (const float*)d_in[13];
  const float* Wo = (const float*)d_in[14];
  const float* W1 = (const float*)d_in[15];
  const float* W2 = (const float*)d_in[16];
  const float* bq = (const float*)d_in[17];
  const float* bk = (const float*)d_in[18];
  const float* bv = (const float*)d_in[19];
  const float* bo = (const float*)d_in[20];
  const float* b1 = (const float*)d_in[21];
  const float* b2 = (const float*)d_in[22];
  const float* ln1_b = (const float*)d_in[23];
  const float* ln2_b = (const float*)d_in[24];
  const float* norm_b = (const float*)d_in[25];
  const float* catb   = (const float*)d_in[26];
  const float* ln1_g = (const float*)d_in[27];
  const float* ln2_g = (const float*)d_in[28];
  const float* norm_g = (const float*)d_in[29];
  const float* pW[7]; const float* pb[7];
  for (int i=0;i<7;i++){ pW[i]=(const float*)d_in[30+2*i]; pb[i]=(const float*)d_in[31+2*i]; }
  const float* catW = (const float*)d_in[44];
  float* outp = (float*)d_out;

  float* wsf = (float*)d_ws;
  size_t off = 0;
  auto alloc = [&](size_t n){ float* p = wsf + off; off += n; return p; };
  float* x   = alloc((size_t)NM*ND);
  float* qb  = alloc((size_t)NM*ND);
  float* kb  = alloc((size_t)NM*ND);
  float* vb  = alloc((size_t)NM*ND);
  float* ab  = alloc((size_t)NM*ND);
  float* tb  = alloc((size_t)NM*ND);
  float* hb  = alloc((size_t)NM*NFF);     // aliases: xe[NM,1248], ffn hidden[NM,2048], xc_in[NM,544]
  float* rc  = alloc((size_t)NS*32);
  float* rs  = alloc((size_t)NS*32);
  float* pe  = alloc(ND);
  float* ckv = alloc((size_t)NB*NH*NCH*NHD*NHD);
  float* cks = alloc((size_t)NB*NH*NCH*NHD);
  float* pkv = alloc((size_t)NB*NH*NCH*NHD*NHD);
  float* pks = alloc((size_t)NB*NH*NCH*NHD);
  float* pwc = alloc((size_t)512*343);
  float* pbc = alloc(343);

  auto gemm = [&](const float* A, const float* Bm, const float* bias, float* C,
                  int Mx, int N, int K, int ldc, float scale, int act){
    dim3 grid((N+63)/64, Mx/64);
    k_gemm<<<grid, 256, 0, stream>>>(A, Bm, bias, C, Mx, N, K, ldc, scale, act);
  };

  // tables + embedding + input projection + PE
  k_tables<<<256, 256, 0, stream>>>(rc, rs, pe);
  k_embed<<<NM, 256, 0, stream>>>(inputs, emb[0],emb[1],emb[2],emb[3],emb[4],emb[5],emb[6], hb);
  gemm(hb, in_W, in_b, x, NM, ND, NE, ND, 1.0f, 0);
  k_addpe<<<NM, 256, 0, stream>>>(x, pe);

  dim3 agrid(NCH, NH, NB);
  for (int l = 0; l < NL; l++){
    const float* wq = Wq + (size_t)l*ND*ND;
    const float* wk = Wk + (size_t)l*ND*ND;
    const float* wv = Wv + (size_t)l*ND*ND;
    const float* wo = Wo + (size_t)l*ND*ND;
    gemm(x, wq, bq + l*ND, qb, NM, ND, ND, ND, 1.0f, 0);
    gemm(x, wk, bk + l*ND, kb, NM, ND, ND, ND, 1.0f, 0);
    gemm(x, wv, bv + l*ND, vb, NM, ND, ND, ND, 1.0f, 0);
    k_ropephi<<<NM, 256, 0, stream>>>(qb, kb, rc, rs);
    k_att1<<<agrid, 256, 0, stream>>>(kb, vb, ckv, cks);
    k_att2<<<NB*NH, 256, 0, stream>>>(ckv, cks, pkv, pks);
    k_att3<<<agrid, 256, 0, stream>>>(qb, kb, vb, pkv, pks, ab);
    gemm(ab, wo, bo + l*ND, tb, NM, ND, ND, ND, 1.0f, 0);
    k_ln<<<NM, 256, 0, stream>>>(x, tb, x, ln1_g + l*ND, ln1_b + l*ND);
    gemm(x, W1 + (size_t)l*ND*NFF, b1 + l*NFF, hb, NM, NFF, ND, NFF, 1.0f, 1);  // GELU
    gemm(hb, W2 + (size_t)l*NFF*ND, b2 + l*ND, tb, NM, ND, NFF, ND, 1.0f, 0);
    k_ln<<<NM, 256, 0, stream>>>(x, tb, x, ln2_g + l*ND, ln2_b + l*ND);
  }

  // final LN
  k_ln<<<NM, 256, 0, stream>>>(x, nullptr, x, norm_g, norm_b);

  // heads: xc = [x | emb_type(target)] @ catW + catb ; big packed projection ; type head overwrite
  k_xc<<<NM, 256, 0, stream>>>(x, target, emb[3], hb);
  gemm(hb, catW, catb, ab, NM, ND, 544, ND, 1.0f, 0);
  k_pack<<<687, 256, 0, stream>>>(pW[0],pW[1],pW[2],pW[3],pW[4],pW[5],pW[6],
                                  pb[0],pb[1],pb[2],pb[3],pb[4],pb[5],pb[6], pwc, pbc);
  gemm(ab, pwc, pbc, outp, NM, 343, ND, 343, 1.0f, 0);
  gemm(x, pW[3], pb[3], outp + 209, NM, 4, ND, 343, 2.0f, 0);
}

// Round 2
// 1906.257 us; speedup vs baseline: 2.4968x; 2.4968x over previous
//
#include <hip/hip_runtime.h>
#include <math.h>

typedef unsigned short u16;
typedef short bf16x8 __attribute__((ext_vector_type(8)));
typedef float f32x4 __attribute__((ext_vector_type(4)));

#define NB 2
#define NS 2048
#define ND 512
#define NH 8
#define NHD 64
#define NL 8
#define NFF 2048
#define NM (NB*NS)      // 4096 rows
#define NE 1248
#define NEP 1280        // padded K for input proj
#define NXC 576         // padded K for cat proj (544 -> 576)
#define CHK 64
#define NCH (NS/CHK)    // 32 chunks

__device__ inline float b2f(u16 u){ union{ unsigned int i; float f;} x; x.i = ((unsigned int)u)<<16; return x.f; }
__device__ inline u16 f2b(float f){ union{ float f; unsigned int i;} x; x.f=f; unsigned int r = x.i + 0x7fffu + ((x.i>>16)&1u); return (u16)(r>>16); }

// ---------------------------------------------------------------- tables
__global__ void k_tables(float* rc, float* rs, float* pe){
  int tid = blockIdx.x*blockDim.x + threadIdx.x;
  if (tid < NS*32){
    int s = tid >> 5, j = tid & 31;
    double inv = exp(-(double)(2*j) * log(10000.0) / (double)NHD);
    double ang = (double)s * inv;
    rc[tid] = (float)cos(ang);
    rs[tid] = (float)sin(ang);
  }
  if (tid < ND/2){
    double div = exp(-(double)(2*tid) * log(10000.0) / (double)ND);
    double ang = (double)NS * div;
    pe[2*tid]   = (float)sin(ang);
    pe[2*tid+1] = (float)cos(ang);
  }
}

// ---------------------------------------------------------------- embedding gather+concat (scaled) -> bf16, K padded to 1280
__global__ void k_embed(const int* __restrict__ inp,
    const float* __restrict__ e0, const float* __restrict__ e1, const float* __restrict__ e2,
    const float* __restrict__ e3, const float* __restrict__ e4, const float* __restrict__ e5,
    const float* __restrict__ e6, u16* __restrict__ xe)
{
  int row = blockIdx.x;
  int i0 = inp[row*7+0], i1 = inp[row*7+1], i2 = inp[row*7+2], i3 = inp[row*7+3],
      i4 = inp[row*7+4], i5 = inp[row*7+5], i6 = inp[row*7+6];
  size_t base = (size_t)row*NEP;
  for (int c = threadIdx.x; c < NEP; c += 256){
    float val = 0.f;
    if      (c < 128)  val = e0[i0*128 + c]        * 11.3137084990f;
    else if (c < 384)  val = e1[i1*256 + (c-128)]  * 16.0f;
    else if (c < 448)  val = e2[i2*64  + (c-384)]  * 8.0f;
    else if (c < 480)  val = e3[i3*32  + (c-448)]  * 5.6568542495f;
    else if (c < 992)  val = e4[i4*512 + (c-480)]  * 22.6274169980f;
    else if (c < 1120) val = e5[i5*128 + (c-992)]  * 11.3137084990f;
    else if (c < NE)   val = e6[i6*128 + (c-1120)] * 11.3137084990f;
    xe[base + c] = f2b(val);
  }
}

// ---------------------------------------------------------------- fp32 [K][N] -> bf16 [N][Kpad] transpose/convert (zero pad k>=K)
__device__ inline void trans_tile(const float* __restrict__ W, u16* __restrict__ WT,
                                  int K, int N, int Kpad){
  __shared__ float t[32][33];
  int tx = threadIdx.x & 31, ty = threadIdx.x >> 5;
  int k0 = blockIdx.y*32, n0 = blockIdx.x*32;
  #pragma unroll
  for (int i=0;i<4;i++){
    int k = k0 + ty + i*8, n = n0 + tx;
    t[ty+i*8][tx] = (k<K && n<N) ? W[(size_t)k*N + n] : 0.f;
  }
  __syncthreads();
  #pragma unroll
  for (int i=0;i<4;i++){
    int n = n0 + ty + i*8, k = k0 + tx;
    if (n<N && k<Kpad) WT[(size_t)n*Kpad + k] = f2b(t[tx][ty+i*8]);
  }
}
__global__ void k_trans(const float* __restrict__ W, u16* __restrict__ WT, int K, int N, int Kpad){
  trans_tile(W, WT, K, N, Kpad);
}
__global__ void k_trans4(const float* __restrict__ Wq, const float* __restrict__ Wk,
                         const float* __restrict__ Wv, const float* __restrict__ Wo,
                         u16* __restrict__ dst){
  int z = blockIdx.z, l = z>>2, s = z&3;
  const float* W = (s==0?Wq:s==1?Wk:s==2?Wv:Wo) + (size_t)l*ND*ND;
  trans_tile(W, dst + (size_t)z*ND*ND, ND, ND, ND);
}

// ---------------------------------------------------------------- bf16 MFMA GEMM (m97 structure, 128x64 tile, BK=64)
// A: [M][K] bf16 ; BT: [Npad][K] bf16 (Npad = gridDim.x*64, pad rows zero)
// C = act(A@B + bias); Cf fp32 and/or Cb bf16, ldc leading dim, store guard col<N
template<int ACT>
__global__ __launch_bounds__(256) void k_gemm(
    const u16* __restrict__ A, const u16* __restrict__ BT,
    const float* __restrict__ bias, float* __restrict__ Cf, u16* __restrict__ Cb,
    int N, int K, int ldc)
{
  __shared__ u16 As[128*64];
  __shared__ u16 Bs[64*64];
  int tid = threadIdx.x;
  int w = tid >> 6, lane = tid & 63;
  int m0 = blockIdx.y*128, n0 = blockIdx.x*64;
  f32x4 acc[4][2];
  #pragma unroll
  for (int m=0;m<4;m++)
    #pragma unroll
    for (int n=0;n<2;n++) acc[m][n] = (f32x4){0.f,0.f,0.f,0.f};

  // staging: wave w covers A rows [w*32,w*32+32), B rows [w*16,w*16+16)
  const u16* ag = A  + (size_t)(m0 + w*32 + (lane>>3))*K + (lane&7)*8;
  const u16* bg = BT + (size_t)(n0 + w*16 + (lane>>3))*K + (lane&7)*8;
  u16* as_base = &As[(w*32)*64];
  u16* bs_base = &Bs[(w*16)*64];
  int wrow = (w>>1)*64, wcol = (w&1)*32;
  int lr = lane & 15, lk = (lane>>4)*8;

  for (int k0 = 0; k0 < K; k0 += 64){
    #pragma unroll
    for (int i=0;i<4;i++)
      __builtin_amdgcn_global_load_lds(
        (__attribute__((address_space(1))) void*)(void*)(ag + (size_t)(i*8)*K + k0),
        (__attribute__((address_space(3))) void*)(as_base + i*8*64), 16, 0, 0);
    #pragma unroll
    for (int j=0;j<2;j++)
      __builtin_amdgcn_global_load_lds(
        (__attribute__((address_space(1))) void*)(void*)(bg + (size_t)(j*8)*K + k0),
        (__attribute__((address_space(3))) void*)(bs_base + j*8*64), 16, 0, 0);
    __syncthreads();
    #pragma unroll
    for (int kk=0;kk<2;kk++){
      bf16x8 af[4], bfr[2];
      #pragma unroll
      for (int m=0;m<4;m++) af[m] = *(const bf16x8*)&As[(wrow + m*16 + lr)*64 + kk*32 + lk];
      #pragma unroll
      for (int n=0;n<2;n++) bfr[n] = *(const bf16x8*)&Bs[(wcol + n*16 + lr)*64 + kk*32 + lk];
      #pragma unroll
      for (int m=0;m<4;m++)
        #pragma unroll
        for (int n=0;n<2;n++)
          acc[m][n] = __builtin_amdgcn_mfma_f32_16x16x32_bf16(af[m], bfr[n], acc[m][n], 0,0,0);
    }
    __syncthreads();
  }
  #pragma unroll
  for (int n=0;n<2;n++){
    int col = n0 + wcol + n*16 + lr;
    if (col < N){
      float bv = bias ? bias[col] : 0.f;
      #pragma unroll
      for (int m=0;m<4;m++){
        #pragma unroll
        for (int r=0;r<4;r++){
          int row = m0 + wrow + m*16 + (lane>>4)*4 + r;
          float v = acc[m][n][r] + bv;
          if (ACT==1) v = 0.5f*v*(1.f+erff(v*0.70710678118654752f));
          if (Cf) Cf[(size_t)row*ldc + col] = v;
          if (Cb) Cb[(size_t)row*ldc + col] = f2b(v);
        }
      }
    }
  }
}

// ---------------------------------------------------------------- x += pe ; xb = bf16(x)
__global__ void k_addpe(float* __restrict__ x, const float* __restrict__ pe, u16* __restrict__ xb){
  int row = blockIdx.x, tid = threadIdx.x;
  size_t b = (size_t)row*ND;
  float v0 = x[b+tid] + pe[tid];
  float v1 = x[b+tid+256] + pe[tid+256];
  x[b+tid]=v0; x[b+tid+256]=v1;
  xb[b+tid]=f2b(v0); xb[b+tid+256]=f2b(v1);
}

// ---------------------------------------------------------------- RoPE + phi (elu+1), in-place on bf16 q,k
__global__ void k_ropephi(u16* __restrict__ q, u16* __restrict__ kb,
                          const float* __restrict__ rc, const float* __restrict__ rs){
  int idx = blockIdx.x*256 + threadIdx.x;
  int row = idx >> 8;
  int p = idx & 255;
  int h = p >> 5, j = p & 31;
  int s = row & (NS-1);
  float c = rc[s*32+j], sn = rs[s*32+j];
  size_t i1 = (size_t)row*ND + h*NHD + j, i2 = i1 + 32;
  float q1=b2f(q[i1]), q2=b2f(q[i2]);
  float r1 = q1*c - q2*sn, r2 = q2*c + q1*sn;
  q[i1] = f2b((r1 > 0.f) ? r1+1.f : expf(r1));
  q[i2] = f2b((r2 > 0.f) ? r2+1.f : expf(r2));
  float k1=b2f(kb[i1]), k2=b2f(kb[i2]);
  r1 = k1*c - k2*sn; r2 = k2*c + k1*sn;
  kb[i1] = f2b((r1 > 0.f) ? r1+1.f : expf(r1));
  kb[i2] = f2b((r2 > 0.f) ? r2+1.f : expf(r2));
}

// ---------------------------------------------------------------- attention phase 1: per-chunk KV outer-sum + K sum
__global__ __launch_bounds__(256) void k_att1(const u16* __restrict__ kb, const u16* __restrict__ v,
    float* __restrict__ ckv, float* __restrict__ cks)
{
  int c = blockIdx.x, h = blockIdx.y, b = blockIdx.z;
  __shared__ float Ks[CHK][NHD];
  __shared__ float Vs[CHK][NHD];
  int tid = threadIdx.x;
  for (int e = tid; e < CHK*NHD; e += 256){
    int t = e >> 6, d = e & 63;
    size_t g = ((size_t)(b*NS + c*CHK + t))*ND + h*NHD + d;
    Ks[t][d] = b2f(kb[g]); Vs[t][d] = b2f(v[g]);
  }
  __syncthreads();
  size_t obase = ((size_t)(b*NH + h))*NCH + c;
  #pragma unroll
  for (int i2 = 0; i2 < 16; i2++){
    int e = tid + i2*256;
    int m = e >> 6, dd = e & 63;
    float s = 0.f;
    #pragma unroll 8
    for (int t = 0; t < 64; t++) s += Ks[t][m]*Vs[t][dd];
    ckv[obase*4096 + e] = s;
  }
  if (tid < 64){
    float s = 0.f;
    #pragma unroll 8
    for (int t = 0; t < 64; t++) s += Ks[t][tid];
    cks[obase*64 + tid] = s;
  }
}

// ---------------------------------------------------------------- attention phase 2: in-place exclusive prefix over chunks
__global__ __launch_bounds__(256) void k_att2(float* __restrict__ ckv, float* __restrict__ cks){
  int bh = blockIdx.y;
  int e = blockIdx.x*256 + threadIdx.x;   // 4096 elements
  size_t base = (size_t)bh*NCH*4096 + e;
  float run = 0.f;
  for (int c = 0; c < NCH; c++){
    float v = ckv[base + (size_t)c*4096];
    ckv[base + (size_t)c*4096] = run;
    run += v;
  }
  if (blockIdx.x == 0 && threadIdx.x < 64){
    size_t kb2 = (size_t)bh*NCH*64 + threadIdx.x;
    float rk = 0.f;
    for (int c = 0; c < NCH; c++){
      float v = cks[kb2 + (size_t)c*64];
      cks[kb2 + (size_t)c*64] = rk;
      rk += v;
    }
  }
}

// ---------------------------------------------------------------- attention phase 3: in-chunk triangular part + output (bf16)
__global__ __launch_bounds__(256) void k_att3(const u16* __restrict__ q, const u16* __restrict__ kb,
    const u16* __restrict__ v, const float* __restrict__ pkv, const float* __restrict__ pks,
    u16* __restrict__ outa)
{
  int c = blockIdx.x, h = blockIdx.y, b = blockIdx.z;
  __shared__ float Ks[CHK][NHD+1];
  __shared__ float Qs[CHK][NHD];
  __shared__ float Vs[CHK][NHD];
  int tid = threadIdx.x;
  for (int e = tid; e < CHK*NHD; e += 256){
    int t = e >> 6, d = e & 63;
    size_t g = ((size_t)(b*NS + c*CHK + t))*ND + h*NHD + d;
    Ks[t][d] = b2f(kb[g]); Qs[t][d] = b2f(q[g]); Vs[t][d] = b2f(v[g]);
  }
  __syncthreads();
  int lane = tid & 63, w = tid >> 6;
  const float* pkvc = pkv + (((size_t)(b*NH + h))*NCH + c)*4096;
  const float* pksc = pks + (((size_t)(b*NH + h))*NCH + c)*64;
  for (int ii = 0; ii < 16; ii++){
    int i = w*16 + ii;
    float sc = 0.f;
    if (lane <= i){
      #pragma unroll 8
      for (int m = 0; m < 64; m++) sc += Qs[i][m]*Ks[lane][m];
    }
    float accv = 0.f, dacc = 0.f;
    #pragma unroll 4
    for (int m = 0; m < 64; m++){
      float qm = Qs[i][m];
      accv += qm * pkvc[m*64 + lane];
      dacc += qm * pksc[m];
    }
    float rowsum = 0.f;
    for (int t2 = 0; t2 < 64; t2++){
      float s_t = __shfl(sc, t2, 64);
      accv += s_t * Vs[t2][lane];
      rowsum += s_t;
    }
    float z = 1.0f / (dacc + rowsum + 1e-6f);
    outa[((size_t)(b*NS + c*CHK + i))*ND + h*NHD + lane] = f2b(accv * z);
  }
}

// ---------------------------------------------------------------- layernorm (optional residual), fp32 out + optional bf16 out
__global__ __launch_bounds__(256) void k_ln(const float* __restrict__ xin, const float* __restrict__ res,
    float* __restrict__ outx, u16* __restrict__ outb,
    const float* __restrict__ g, const float* __restrict__ bvec)
{
  int row = blockIdx.x, tid = threadIdx.x;
  size_t base = (size_t)row*ND;
  float v0 = xin[base+tid], v1 = xin[base+tid+256];
  if (res){ v0 += res[base+tid]; v1 += res[base+tid+256]; }
  float s = v0+v1, ss2 = v0*v0 + v1*v1;
  #pragma unroll
  for (int o = 32; o >= 1; o >>= 1){
    s   += __shfl_down(s, o, 64);
    ss2 += __shfl_down(ss2, o, 64);
  }
  __shared__ float red[8];
  int wv = tid >> 6, ln = tid & 63;
  if (ln == 0){ red[wv] = s; red[4+wv] = ss2; }
  __syncthreads();
  float stot  = red[0]+red[1]+red[2]+red[3];
  float sstot = red[4]+red[5]+red[6]+red[7];
  float mean = stot * (1.0f/ND);
  float var  = sstot * (1.0f/ND) - mean*mean;
  float inv = 1.0f / sqrtf(var + 1e-5f);
  float o0 = (v0-mean)*inv*g[tid]     + bvec[tid];
  float o1 = (v1-mean)*inv*g[tid+256] + bvec[tid+256];
  outx[base+tid] = o0; outx[base+tid+256] = o1;
  if (outb){ outb[base+tid] = f2b(o0); outb[base+tid+256] = f2b(o1); }
}

// ---------------------------------------------------------------- build xc = [x | emb_type(target)*sqrt(32) | pad] bf16, K=576
__global__ void k_xc(const float* __restrict__ x, const int* __restrict__ tgt,
                     const float* __restrict__ embt, u16* __restrict__ xc){
  int row = blockIdx.x;
  int id = tgt[row*7+3];
  size_t base = (size_t)row*NXC;
  for (int c = threadIdx.x; c < NXC; c += 256){
    float v = (c < ND) ? x[(size_t)row*ND + c]
            : (c < 544 ? embt[id*32 + (c-ND)]*5.6568542495f : 0.f);
    xc[base + c] = f2b(v);
  }
}

// ---------------------------------------------------------------- pack head weights transposed+pre-scaled
__global__ void k_pack(const float* p0,const float* p1,const float* p2,const float* p3,
                       const float* p4,const float* p5,const float* p6,
                       const float* q0,const float* q1,const float* q2,const float* q3,
                       const float* q4,const float* q5,const float* q6,
                       u16* __restrict__ pwcT, float* __restrict__ pbc,
                       u16* __restrict__ ptT, float* __restrict__ pbt){
  int idx = blockIdx.x*256 + threadIdx.x;   // 384*512
  const int off[8] = {0,56,191,209,213,300,318,343};
  int col = idx >> 9, k = idx & 511;
  if (col < 384){
    u16 v = 0;
    if (col < 343){
      int f = 0;
      while (col >= off[f+1]) f++;
      int cc = col - off[f];
      int V = off[f+1]-off[f];
      const float* P = (f==0)?p0:(f==1)?p1:(f==2)?p2:(f==3)?p3:(f==4)?p4:(f==5)?p5:p6;
      v = f2b(P[(size_t)k*V + cc] * sqrtf((float)V));
    }
    pwcT[(size_t)col*512 + k] = v;
  }
  if (idx < 64*512){
    int n = idx >> 9;
    ptT[idx] = (n < 4) ? f2b(p3[(size_t)k*4 + n]*2.0f) : (u16)0;
  }
  if (idx < 343){
    int c2 = idx, f = 0;
    while (c2 >= off[f+1]) f++;
    int cc = c2 - off[f]; int V = off[f+1]-off[f];
    const float* Q = (f==0)?q0:(f==1)?q1:(f==2)?q2:(f==3)?q3:(f==4)?q4:(f==5)?q5:q6;
    pbc[idx] = Q[cc]*sqrtf((float)V);
  }
  if (idx < 4) pbt[idx] = q3[idx]*2.0f;
}

// ================================================================ host
extern "C" void kernel_launch(void* const* d_in, const int* in_sizes, int n_in,
                              void* d_out, int out_size, void* d_ws, size_t ws_size,
                              hipStream_t stream)
{
  const int* inputs = (const int*)d_in[0];
  const int* target = (const int*)d_in[1];
  const float* emb[7];
  for (int i=0;i<7;i++) emb[i] = (const float*)d_in[2+i];
  const float* in_W  = (const float*)d_in[9];
  const float* in_b  = (const float*)d_in[10];
  const float* Wq = (const float*)d_in[11];
  const float* Wk = (const float*)d_in[12];
  const float* Wv = (const float*)d_in[13];
  const float* Wo = (const float*)d_in[14];
  const float* W1 = (const float*)d_in[15];
  const float* W2 = (const float*)d_in[16];
  const float* bq = (const float*)d_in[17];
  const float* bk = (const float*)d_in[18];
  const float* bv = (const float*)d_in[19];
  const float* bo = (const float*)d_in[20];
  const float* b1 = (const float*)d_in[21];
  const float* b2 = (const float*)d_in[22];
  const float* ln1_b = (const float*)d_in[23];
  const float* ln2_b = (const float*)d_in[24];
  const float* norm_b = (const float*)d_in[25];
  const float* catb   = (const float*)d_in[26];
  const float* ln1_g = (const float*)d_in[27];
  const float* ln2_g = (const float*)d_in[28];
  const float* norm_g = (const float*)d_in[29];
  const float* pW[7]; const float* pb[7];
  for (int i=0;i<7;i++){ pW[i]=(const float*)d_in[30+2*i]; pb[i]=(const float*)d_in[31+2*i]; }
  const float* catW = (const float*)d_in[44];
  float* outp = (float*)d_out;

  char* base = (char*)d_ws;
  size_t off = 0;
  auto alloc = [&](size_t bytes)->void*{ void* p = base + off; off += bytes; off = (off + 255) & ~(size_t)255; return p; };

  float* x    = (float*)alloc((size_t)NM*ND*4);
  u16*   xb   = (u16*)  alloc((size_t)NM*ND*2);
  u16*   qb   = (u16*)  alloc((size_t)NM*ND*2);
  u16*   kb   = (u16*)  alloc((size_t)NM*ND*2);
  u16*   vb   = (u16*)  alloc((size_t)NM*ND*2);
  float* tb   = (float*)alloc((size_t)NM*ND*4);
  u16*   ab   = (u16*)  alloc((size_t)NM*ND*2);
  u16*   hb   = (u16*)  alloc((size_t)NM*NFF*2);   // aliases: xe[NM,1280] bf16, xc[NM,576]+oc[NM,512] bf16
  float* rc   = (float*)alloc((size_t)NS*32*4);
  float* rs   = (float*)alloc((size_t)NS*32*4);
  float* pe   = (float*)alloc(ND*4);
  float* ckv  = (float*)alloc((size_t)NB*NH*NCH*NHD*NHD*4);
  float* cks  = (float*)alloc((size_t)NB*NH*NCH*NHD*4);
  u16*  qkvoT = (u16*)  alloc((size_t)NL*4*ND*ND*2);
  u16*  w1T   = (u16*)  alloc((size_t)NFF*ND*2);   // per-layer reuse
  u16*  w2T   = (u16*)  alloc((size_t)ND*NFF*2);   // per-layer reuse
  u16*  inWT  = (u16*)  alloc((size_t)ND*NEP*2);
  u16*  catWT = (u16*)  alloc((size_t)ND*NXC*2);
  u16*  pwcT  = (u16*)  alloc((size_t)384*512*2);
  float* pbc  = (float*)alloc(344*4);
  u16*  ptT   = (u16*)  alloc((size_t)64*512*2);
  float* pbt  = (float*)alloc(4*4);
  u16*  xeb = hb;                       // [NM][1280]
  u16*  xcb = hb;                       // [NM][576]
  u16*  ocb = hb + (size_t)NM*NXC;      // [NM][512]

  auto gemm = [&](const u16* A, const u16* BT, const float* bias, float* Cf, u16* Cb,
                  int ntile, int N, int K, int ldc, int act){
    dim3 g(ntile, NM/128);
    if (act) k_gemm<1><<<g, 256, 0, stream>>>(A, BT, bias, Cf, Cb, N, K, ldc);
    else     k_gemm<0><<<g, 256, 0, stream>>>(A, BT, bias, Cf, Cb, N, K, ldc);
  };

  // tables + weight prep
  k_tables<<<256, 256, 0, stream>>>(rc, rs, pe);
  k_trans4<<<dim3(16,16,32), 256, 0, stream>>>(Wq, Wk, Wv, Wo, qkvoT);
  k_trans<<<dim3(16,40), 256, 0, stream>>>(in_W, inWT, NE, ND, NEP);
  k_trans<<<dim3(16,18), 256, 0, stream>>>(catW, catWT, 544, ND, NXC);
  k_pack<<<768, 256, 0, stream>>>(pW[0],pW[1],pW[2],pW[3],pW[4],pW[5],pW[6],
                                  pb[0],pb[1],pb[2],pb[3],pb[4],pb[5],pb[6],
                                  pwcT, pbc, ptT, pbt);

  // embedding + input projection + PE
  k_embed<<<NM, 256, 0, stream>>>(inputs, emb[0],emb[1],emb[2],emb[3],emb[4],emb[5],emb[6], xeb);
  gemm(xeb, inWT, in_b, x, nullptr, ND/64, ND, NEP, ND, 0);
  k_addpe<<<NM, 256, 0, stream>>>(x, pe, xb);

  dim3 agrid(NCH, NH, NB);
  for (int l = 0; l < NL; l++){
    k_trans<<<dim3(64,16), 256, 0, stream>>>(W1 + (size_t)l*ND*NFF, w1T, ND, NFF, ND);
    k_trans<<<dim3(16,64), 256, 0, stream>>>(W2 + (size_t)l*NFF*ND, w2T, NFF, ND, NFF);
    const u16* wqT = qkvoT + (size_t)(l*4+0)*ND*ND;
    const u16* wkT = qkvoT + (size_t)(l*4+1)*ND*ND;
    const u16* wvT = qkvoT + (size_t)(l*4+2)*ND*ND;
    const u16* woT = qkvoT + (size_t)(l*4+3)*ND*ND;
    gemm(xb, wqT, bq + l*ND, nullptr, qb, ND/64, ND, ND, ND, 0);
    gemm(xb, wkT, bk + l*ND, nullptr, kb, ND/64, ND, ND, ND, 0);
    gemm(xb, wvT, bv + l*ND, nullptr, vb, ND/64, ND, ND, ND, 0);
    k_ropephi<<<NM, 256, 0, stream>>>(qb, kb, rc, rs);
    k_att1<<<agrid, 256, 0, stream>>>(kb, vb, ckv, cks);
    k_att2<<<dim3(16,16), 256, 0, stream>>>(ckv, cks);
    k_att3<<<agrid, 256, 0, stream>>>(qb, kb, vb, ckv, cks, ab);
    gemm(ab, woT, bo + l*ND, tb, nullptr, ND/64, ND, ND, ND, 0);
    k_ln<<<NM, 256, 0, stream>>>(x, tb, x, xb, ln1_g + l*ND, ln1_b + l*ND);
    gemm(xb, w1T, b1 + l*NFF, nullptr, hb, NFF/64, NFF, ND, NFF, 1);   // GELU -> bf16 hidden
    gemm(hb, w2T, b2 + l*ND, tb, nullptr, ND/64, ND, NFF, ND, 0);
    k_ln<<<NM, 256, 0, stream>>>(x, tb, x, xb, ln2_g + l*ND, ln2_b + l*ND);
  }

  // final LN
  k_ln<<<NM, 256, 0, stream>>>(x, nullptr, x, xb, norm_g, norm_b);

  // heads
  k_xc<<<NM, 256, 0, stream>>>(x, target, emb[3], xcb);
  gemm(xcb, catWT, catb, nullptr, ocb, ND/64, ND, NXC, ND, 0);
  gemm(ocb, pwcT, pbc, outp, nullptr, 6, 343, ND, 343, 0);
  gemm(xb, ptT, pbt, outp + 209, nullptr, 1, 4, ND, 343, 0);
}

// Round 3
// 1211.064 us; speedup vs baseline: 3.9300x; 1.5740x over previous
//
#include <hip/hip_runtime.h>
#include <math.h>

typedef unsigned short u16;
typedef short bf16x8 __attribute__((ext_vector_type(8)));
typedef float f32x4 __attribute__((ext_vector_type(4)));
typedef u16 u16x4 __attribute__((ext_vector_type(4)));
typedef u16 u16x8 __attribute__((ext_vector_type(8)));

#define NB 2
#define NS 2048
#define ND 512
#define NH 8
#define NHD 64
#define NL 8
#define NFF 2048
#define NM (NB*NS)      // 4096 rows
#define NE 1248
#define NEP 1280        // padded K for input proj
#define NXC 576         // padded K for cat proj (544 -> 576)
#define CHK 64
#define NCH (NS/CHK)    // 32 chunks
#define QKVW 1536       // fused qkv row width

__device__ inline float b2f(u16 u){ union{ unsigned int i; float f;} x; x.i = ((unsigned int)u)<<16; return x.f; }
__device__ inline u16 f2b(float f){ union{ float f; unsigned int i;} x; x.f=f; unsigned int r = x.i + 0x7fffu + ((x.i>>16)&1u); return (u16)(r>>16); }

// ---------------------------------------------------------------- tables
__global__ void k_tables(float* rc, float* rs, float* pe){
  int tid = blockIdx.x*blockDim.x + threadIdx.x;
  if (tid < NS*32){
    int s = tid >> 5, j = tid & 31;
    double inv = exp(-(double)(2*j) * log(10000.0) / (double)NHD);
    double ang = (double)s * inv;
    rc[tid] = (float)cos(ang);
    rs[tid] = (float)sin(ang);
  }
  if (tid < ND/2){
    double div = exp(-(double)(2*tid) * log(10000.0) / (double)ND);
    double ang = (double)NS * div;
    pe[2*tid]   = (float)sin(ang);
    pe[2*tid+1] = (float)cos(ang);
  }
}

// ---------------------------------------------------------------- embedding gather+concat (scaled) -> bf16, K padded to 1280
__global__ void k_embed(const int* __restrict__ inp,
    const float* __restrict__ e0, const float* __restrict__ e1, const float* __restrict__ e2,
    const float* __restrict__ e3, const float* __restrict__ e4, const float* __restrict__ e5,
    const float* __restrict__ e6, u16* __restrict__ xe)
{
  int row = blockIdx.x;
  int i0 = inp[row*7+0], i1 = inp[row*7+1], i2 = inp[row*7+2], i3 = inp[row*7+3],
      i4 = inp[row*7+4], i5 = inp[row*7+5], i6 = inp[row*7+6];
  size_t base = (size_t)row*NEP;
  for (int c = threadIdx.x; c < NEP; c += 256){
    float val = 0.f;
    if      (c < 128)  val = e0[i0*128 + c]        * 11.3137084990f;
    else if (c < 384)  val = e1[i1*256 + (c-128)]  * 16.0f;
    else if (c < 448)  val = e2[i2*64  + (c-384)]  * 8.0f;
    else if (c < 480)  val = e3[i3*32  + (c-448)]  * 5.6568542495f;
    else if (c < 992)  val = e4[i4*512 + (c-480)]  * 22.6274169980f;
    else if (c < 1120) val = e5[i5*128 + (c-992)]  * 11.3137084990f;
    else if (c < NE)   val = e6[i6*128 + (c-1120)] * 11.3137084990f;
    xe[base + c] = f2b(val);
  }
}

// ---------------------------------------------------------------- fp32 [K][N] -> bf16 [N][Kpad] transpose/convert (zero pad k>=K)
__device__ inline void trans_tile(const float* __restrict__ W, u16* __restrict__ WT,
                                  int K, int N, int Kpad){
  __shared__ float t[32][33];
  int tx = threadIdx.x & 31, ty = threadIdx.x >> 5;
  int k0 = blockIdx.y*32, n0 = blockIdx.x*32;
  #pragma unroll
  for (int i=0;i<4;i++){
    int k = k0 + ty + i*8, n = n0 + tx;
    t[ty+i*8][tx] = (k<K && n<N) ? W[(size_t)k*N + n] : 0.f;
  }
  __syncthreads();
  #pragma unroll
  for (int i=0;i<4;i++){
    int n = n0 + ty + i*8, k = k0 + tx;
    if (n<N && k<Kpad) WT[(size_t)n*Kpad + k] = f2b(t[tx][ty+i*8]);
  }
}
__global__ void k_trans(const float* __restrict__ W, u16* __restrict__ WT, int K, int N, int Kpad){
  trans_tile(W, WT, K, N, Kpad);
}
__global__ void k_trans4(const float* __restrict__ Wq, const float* __restrict__ Wk,
                         const float* __restrict__ Wv, const float* __restrict__ Wo,
                         u16* __restrict__ dst){
  int z = blockIdx.z, l = z>>2, s = z&3;
  const float* W = (s==0?Wq:s==1?Wk:s==2?Wv:Wo) + (size_t)l*ND*ND;
  trans_tile(W, dst + (size_t)z*ND*ND, ND, ND, ND);
}

// ---------------------------------------------------------------- bf16 MFMA GEMM (m97 structure, 128x64 tile, BK=64)
template<int ACT>
__global__ __launch_bounds__(256) void k_gemm(
    const u16* __restrict__ A, const u16* __restrict__ BT,
    const float* __restrict__ bias, float* __restrict__ Cf, u16* __restrict__ Cb,
    int N, int K, int ldc)
{
  __shared__ u16 As[128*64];
  __shared__ u16 Bs[64*64];
  int tid = threadIdx.x;
  int w = tid >> 6, lane = tid & 63;
  int m0 = blockIdx.y*128, n0 = blockIdx.x*64;
  f32x4 acc[4][2];
  #pragma unroll
  for (int m=0;m<4;m++)
    #pragma unroll
    for (int n=0;n<2;n++) acc[m][n] = (f32x4){0.f,0.f,0.f,0.f};

  const u16* ag = A  + (size_t)(m0 + w*32 + (lane>>3))*K + (lane&7)*8;
  const u16* bg = BT + (size_t)(n0 + w*16 + (lane>>3))*K + (lane&7)*8;
  u16* as_base = &As[(w*32)*64];
  u16* bs_base = &Bs[(w*16)*64];
  int wrow = (w>>1)*64, wcol = (w&1)*32;
  int lr = lane & 15, lk = (lane>>4)*8;

  for (int k0 = 0; k0 < K; k0 += 64){
    #pragma unroll
    for (int i=0;i<4;i++)
      __builtin_amdgcn_global_load_lds(
        (__attribute__((address_space(1))) void*)(void*)(ag + (size_t)(i*8)*K + k0),
        (__attribute__((address_space(3))) void*)(as_base + i*8*64), 16, 0, 0);
    #pragma unroll
    for (int j=0;j<2;j++)
      __builtin_amdgcn_global_load_lds(
        (__attribute__((address_space(1))) void*)(void*)(bg + (size_t)(j*8)*K + k0),
        (__attribute__((address_space(3))) void*)(bs_base + j*8*64), 16, 0, 0);
    __syncthreads();
    #pragma unroll
    for (int kk=0;kk<2;kk++){
      bf16x8 af[4], bfr[2];
      #pragma unroll
      for (int m=0;m<4;m++) af[m] = *(const bf16x8*)&As[(wrow + m*16 + lr)*64 + kk*32 + lk];
      #pragma unroll
      for (int n=0;n<2;n++) bfr[n] = *(const bf16x8*)&Bs[(wcol + n*16 + lr)*64 + kk*32 + lk];
      #pragma unroll
      for (int m=0;m<4;m++)
        #pragma unroll
        for (int n=0;n<2;n++)
          acc[m][n] = __builtin_amdgcn_mfma_f32_16x16x32_bf16(af[m], bfr[n], acc[m][n], 0,0,0);
    }
    __syncthreads();
  }
  #pragma unroll
  for (int n=0;n<2;n++){
    int col = n0 + wcol + n*16 + lr;
    if (col < N){
      float bv = bias ? bias[col] : 0.f;
      #pragma unroll
      for (int m=0;m<4;m++){
        #pragma unroll
        for (int r=0;r<4;r++){
          int row = m0 + wrow + m*16 + (lane>>4)*4 + r;
          float v = acc[m][n][r] + bv;
          if (ACT==1) v = 0.5f*v*(1.f+erff(v*0.70710678118654752f));
          if (Cf) Cf[(size_t)row*ldc + col] = v;
          if (Cb) Cb[(size_t)row*ldc + col] = f2b(v);
        }
      }
    }
  }
}

// ---------------------------------------------------------------- x += pe ; xb = bf16(x)
__global__ void k_addpe(float* __restrict__ x, const float* __restrict__ pe, u16* __restrict__ xb){
  int row = blockIdx.x, tid = threadIdx.x;
  size_t b = (size_t)row*ND;
  float v0 = x[b+tid] + pe[tid];
  float v1 = x[b+tid+256] + pe[tid+256];
  x[b+tid]=v0; x[b+tid+256]=v1;
  xb[b+tid]=f2b(v0); xb[b+tid+256]=f2b(v1);
}

// ---------------------------------------------------------------- RoPE + phi (elu+1) on fused qkv buffer (q and k sections)
__global__ void k_ropephi(u16* __restrict__ qkv, const float* __restrict__ rc, const float* __restrict__ rs){
  int idx = blockIdx.x*256 + threadIdx.x;
  int row = idx >> 8;
  int p = idx & 255;
  int h = p >> 5, j = p & 31;
  int s = row & (NS-1);
  float cc = rc[s*32+j], sn = rs[s*32+j];
  size_t i1 = (size_t)row*QKVW + h*NHD + j, i2 = i1 + 32;
  float q1=b2f(qkv[i1]), q2=b2f(qkv[i2]);
  float r1 = q1*cc - q2*sn, r2 = q2*cc + q1*sn;
  qkv[i1] = f2b((r1 > 0.f) ? r1+1.f : expf(r1));
  qkv[i2] = f2b((r2 > 0.f) ? r2+1.f : expf(r2));
  float k1=b2f(qkv[i1+512]), k2=b2f(qkv[i2+512]);
  r1 = k1*cc - k2*sn; r2 = k2*cc + k1*sn;
  qkv[i1+512] = f2b((r1 > 0.f) ? r1+1.f : expf(r1));
  qkv[i2+512] = f2b((r2 > 0.f) ? r2+1.f : expf(r2));
}

// ---------------------------------------------------------------- att1: per-chunk [V^T;1]·K -> pref tile [80][64] = [ckv^T ; cks]
__global__ __launch_bounds__(256) void k_att1(const u16* __restrict__ qkv, float* __restrict__ pref){
  int c = blockIdx.x, h = blockIdx.y, b = blockIdx.z;
  __shared__ u16 Kt[64*64];   // [m][t] xor-swizzled
  __shared__ u16 Vt[80*64];   // [d_ext][t] xor-swizzled; row64=ones, 65-79=0
  int tid = threadIdx.x;
  {
    int t = tid & 63, dseg = (tid>>6)*16;
    const u16* kg = qkv + ((size_t)(b*NS + c*CHK + t))*QKVW + 512 + h*NHD + dseg;
    u16x8 k0 = *(const u16x8*)kg;
    u16x8 k1 = *(const u16x8*)(kg+8);
    u16x8 v0 = *(const u16x8*)(kg+512);
    u16x8 v1 = *(const u16x8*)(kg+520);
    #pragma unroll
    for (int e=0;e<8;e++){
      int d0 = dseg+e, d1 = dseg+8+e;
      Kt[(d0*64+t) ^ ((d0&7)<<3)] = k0[e];
      Kt[(d1*64+t) ^ ((d1&7)<<3)] = k1[e];
      Vt[(d0*64+t) ^ ((d0&7)<<3)] = v0[e];
      Vt[(d1*64+t) ^ ((d1&7)<<3)] = v1[e];
    }
    if (tid < 64) Vt[4096 + tid] = 0x3F80;   // ones row (row 64, swz=0)
    for (int e = tid; e < 15*64; e += 256){
      int r = 65 + (e>>6), tt = e&63;
      Vt[(r*64+tt) ^ ((r&7)<<3)] = 0;
    }
  }
  __syncthreads();
  int lane = tid & 63, w = tid >> 6;
  int lr = lane & 15, lk = (lane>>4)*8;
  f32x4 acc[5];
  #pragma unroll
  for (int i=0;i<5;i++) acc[i] = (f32x4){0.f,0.f,0.f,0.f};
  #pragma unroll
  for (int kk=0;kk<2;kk++){
    int mcol = w*16 + lr;
    bf16x8 bfrag = *(const bf16x8*)&Kt[(mcol*64 + kk*32 + lk) ^ ((mcol&7)<<3)];
    #pragma unroll
    for (int fr=0; fr<5; fr++){
      int arow = fr*16 + lr;
      bf16x8 afrag = *(const bf16x8*)&Vt[(arow*64 + kk*32 + lk) ^ ((arow&7)<<3)];
      acc[fr] = __builtin_amdgcn_mfma_f32_16x16x32_bf16(afrag, bfrag, acc[fr], 0,0,0);
    }
  }
  size_t base = (((size_t)(b*NH + h))*NCH + c)*5120;
  int g = lane>>4;
  #pragma unroll
  for (int fr=0; fr<5; fr++)
    #pragma unroll
    for (int r=0;r<4;r++)
      pref[base + (fr*16 + g*4 + r)*64 + w*16 + lr] = acc[fr][r];
}

// ---------------------------------------------------------------- att2: exclusive prefix over 32 chunks, register-pipelined
__global__ __launch_bounds__(256) void k_att2(float* __restrict__ pref){
  int bh = blockIdx.y;
  int e = blockIdx.x*256 + threadIdx.x;   // 0..5119
  size_t base = (size_t)bh*NCH*5120 + e;
  float v[NCH];
  #pragma unroll
  for (int c=0;c<NCH;c++) v[c] = pref[base + (size_t)c*5120];
  float run = 0.f;
  #pragma unroll
  for (int c=0;c<NCH;c++){ float t = v[c]; pref[base + (size_t)c*5120] = run; run += t; }
}

// ---------------------------------------------------------------- att3: MFMA in-chunk attention
// S^T = K·Q^T (masked), O = S·[V|1] + Q·[pkv^T|pks]; col 64 = denominator
__global__ __launch_bounds__(256) void k_att3(const u16* __restrict__ qkv,
    const float* __restrict__ pref, u16* __restrict__ outa)
{
  int c = blockIdx.x, h = blockIdx.y, b = blockIdx.z;
  __shared__ u16 Qs[4096], Ks[4096], Sm[4096];   // [row][64] xor-swz
  __shared__ u16 Vt[5120], Ps[5120];             // [80][64] xor-swz
  __shared__ float dens[64];
  int tid = threadIdx.x;
  {
    int row = tid>>2, seg = (tid&3)*16;
    const u16* qg = qkv + ((size_t)(b*NS + c*CHK + row))*QKVW + h*NHD + seg;
    u16x8 q0 = *(const u16x8*)qg;
    u16x8 q1 = *(const u16x8*)(qg+8);
    u16x8 kk0 = *(const u16x8*)(qg+512);
    u16x8 kk1 = *(const u16x8*)(qg+520);
    int sw = (row&7)<<3;
    *(u16x8*)&Qs[(row*64+seg) ^ sw]     = q0;
    *(u16x8*)&Qs[(row*64+seg+8) ^ sw]   = q1;
    *(u16x8*)&Ks[(row*64+seg) ^ sw]     = kk0;
    *(u16x8*)&Ks[(row*64+seg+8) ^ sw]   = kk1;
  }
  {
    int t = tid&63, dseg = (tid>>6)*16;
    const u16* vg = qkv + ((size_t)(b*NS + c*CHK + t))*QKVW + 1024 + h*NHD + dseg;
    u16x8 v0 = *(const u16x8*)vg;
    u16x8 v1 = *(const u16x8*)(vg+8);
    #pragma unroll
    for (int e=0;e<8;e++){
      int d0=dseg+e, d1=dseg+8+e;
      Vt[(d0*64+t)^((d0&7)<<3)] = v0[e];
      Vt[(d1*64+t)^((d1&7)<<3)] = v1[e];
    }
    if (tid<64) Vt[4096+tid] = 0x3F80;
    for (int e=tid; e<15*64; e+=256){
      int r = 65+(e>>6), tt = e&63;
      Vt[(r*64+tt)^((r&7)<<3)] = 0;
    }
  }
  {
    size_t pb = (((size_t)(b*NH + h))*NCH + c)*5120;
    for (int e=tid; e<5120; e+=256){
      int row = e>>6, m = e&63;
      Ps[(row*64+m)^((row&7)<<3)] = f2b(pref[pb+e]);
    }
  }
  __syncthreads();
  int lane = tid&63, w = tid>>6;
  int lr = lane&15, lk = (lane>>4)*8, g = lane>>4;
  // phase A: S^T[t][i] for this wave's i-strip
  f32x4 sacc[4];
  #pragma unroll
  for (int i=0;i<4;i++) sacc[i] = (f32x4){0.f,0.f,0.f,0.f};
  int iq = w*16 + lr;
  #pragma unroll
  for (int kk=0;kk<2;kk++){
    bf16x8 bq = *(const bf16x8*)&Qs[(iq*64 + kk*32 + lk) ^ ((iq&7)<<3)];
    #pragma unroll
    for (int ft=0; ft<4; ft++){
      int tr = ft*16 + lr;
      bf16x8 ak = *(const bf16x8*)&Ks[(tr*64 + kk*32 + lk) ^ ((tr&7)<<3)];
      sacc[ft] = __builtin_amdgcn_mfma_f32_16x16x32_bf16(ak, bq, sacc[ft], 0,0,0);
    }
  }
  // masked write S[i][t] (b64 per fragment)
  #pragma unroll
  for (int ft=0; ft<4; ft++){
    int t0 = ft*16 + g*4;
    u16x4 pk;
    #pragma unroll
    for (int r=0;r<4;r++) pk[r] = f2b((t0+r <= iq) ? sacc[ft][r] : 0.f);
    *(u16x4*)&Sm[(iq*64 + t0) ^ ((iq&7)<<3)] = pk;
  }
  __syncthreads();
  // phase B: O[i][col] = S·[V|1] + Q·[pkv^T|pks]
  f32x4 acc[5];
  #pragma unroll
  for (int i=0;i<5;i++) acc[i] = (f32x4){0.f,0.f,0.f,0.f};
  #pragma unroll
  for (int kk=0;kk<2;kk++){
    int sw = (iq&7)<<3;
    bf16x8 as = *(const bf16x8*)&Sm[(iq*64 + kk*32 + lk) ^ sw];
    bf16x8 aq = *(const bf16x8*)&Qs[(iq*64 + kk*32 + lk) ^ sw];
    #pragma unroll
    for (int c5=0;c5<5;c5++){
      int col = c5*16 + lr, sw2 = (col&7)<<3;
      bf16x8 bv = *(const bf16x8*)&Vt[(col*64 + kk*32 + lk) ^ sw2];
      bf16x8 bp = *(const bf16x8*)&Ps[(col*64 + kk*32 + lk) ^ sw2];
      acc[c5] = __builtin_amdgcn_mfma_f32_16x16x32_bf16(as, bv, acc[c5], 0,0,0);
      acc[c5] = __builtin_amdgcn_mfma_f32_16x16x32_bf16(aq, bp, acc[c5], 0,0,0);
    }
  }
  if (lr == 0){
    #pragma unroll
    for (int r=0;r<4;r++) dens[w*16 + g*4 + r] = acc[4][r];
  }
  __syncthreads();
  #pragma unroll
  for (int c5=0;c5<4;c5++){
    #pragma unroll
    for (int r=0;r<4;r++){
      int i = w*16 + g*4 + r;
      float z = 1.f/(dens[i] + 1e-6f);
      outa[((size_t)(b*NS + c*CHK + i))*ND + h*NHD + c5*16 + lr] = f2b(acc[c5][r]*z);
    }
  }
}

// ---------------------------------------------------------------- layernorm (optional residual), fp32 out + optional bf16 out
__global__ __launch_bounds__(256) void k_ln(const float* __restrict__ xin, const float* __restrict__ res,
    float* __restrict__ outx, u16* __restrict__ outb,
    const float* __restrict__ g, const float* __restrict__ bvec)
{
  int row = blockIdx.x, tid = threadIdx.x;
  size_t base = (size_t)row*ND;
  float v0 = xin[base+tid], v1 = xin[base+tid+256];
  if (res){ v0 += res[base+tid]; v1 += res[base+tid+256]; }
  float s = v0+v1, ss2 = v0*v0 + v1*v1;
  #pragma unroll
  for (int o = 32; o >= 1; o >>= 1){
    s   += __shfl_down(s, o, 64);
    ss2 += __shfl_down(ss2, o, 64);
  }
  __shared__ float red[8];
  int wv = tid >> 6, ln = tid & 63;
  if (ln == 0){ red[wv] = s; red[4+wv] = ss2; }
  __syncthreads();
  float stot  = red[0]+red[1]+red[2]+red[3];
  float sstot = red[4]+red[5]+red[6]+red[7];
  float mean = stot * (1.0f/ND);
  float var  = sstot * (1.0f/ND) - mean*mean;
  float inv = 1.0f / sqrtf(var + 1e-5f);
  float o0 = (v0-mean)*inv*g[tid]     + bvec[tid];
  float o1 = (v1-mean)*inv*g[tid+256] + bvec[tid+256];
  outx[base+tid] = o0; outx[base+tid+256] = o1;
  if (outb){ outb[base+tid] = f2b(o0); outb[base+tid+256] = f2b(o1); }
}

// ---------------------------------------------------------------- build xc = [x | emb_type(target)*sqrt(32) | pad] bf16, K=576
__global__ void k_xc(const float* __restrict__ x, const int* __restrict__ tgt,
                     const float* __restrict__ embt, u16* __restrict__ xc){
  int row = blockIdx.x;
  int id = tgt[row*7+3];
  size_t base = (size_t)row*NXC;
  for (int c = threadIdx.x; c < NXC; c += 256){
    float v = (c < ND) ? x[(size_t)row*ND + c]
            : (c < 544 ? embt[id*32 + (c-ND)]*5.6568542495f : 0.f);
    xc[base + c] = f2b(v);
  }
}

// ---------------------------------------------------------------- pack head weights transposed+pre-scaled
__global__ void k_pack(const float* p0,const float* p1,const float* p2,const float* p3,
                       const float* p4,const float* p5,const float* p6,
                       const float* q0,const float* q1,const float* q2,const float* q3,
                       const float* q4,const float* q5,const float* q6,
                       u16* __restrict__ pwcT, float* __restrict__ pbc,
                       u16* __restrict__ ptT, float* __restrict__ pbt){
  int idx = blockIdx.x*256 + threadIdx.x;   // 384*512
  const int off[8] = {0,56,191,209,213,300,318,343};
  int col = idx >> 9, k = idx & 511;
  if (col < 384){
    u16 v = 0;
    if (col < 343){
      int f = 0;
      while (col >= off[f+1]) f++;
      int cc = col - off[f];
      int V = off[f+1]-off[f];
      const float* P = (f==0)?p0:(f==1)?p1:(f==2)?p2:(f==3)?p3:(f==4)?p4:(f==5)?p5:p6;
      v = f2b(P[(size_t)k*V + cc] * sqrtf((float)V));
    }
    pwcT[(size_t)col*512 + k] = v;
  }
  if (idx < 64*512){
    int n = idx >> 9;
    ptT[idx] = (n < 4) ? f2b(p3[(size_t)k*4 + n]*2.0f) : (u16)0;
  }
  if (idx < 343){
    int c2 = idx, f = 0;
    while (c2 >= off[f+1]) f++;
    int cc = c2 - off[f]; int V = off[f+1]-off[f];
    const float* Q = (f==0)?q0:(f==1)?q1:(f==2)?q2:(f==3)?q3:(f==4)?q4:(f==5)?q5:q6;
    pbc[idx] = Q[cc]*sqrtf((float)V);
  }
  if (idx < 4) pbt[idx] = q3[idx]*2.0f;
}

// ---------------------------------------------------------------- pack fused qkv bias
__global__ void k_bqkv(const float* __restrict__ bq, const float* __restrict__ bk,
                       const float* __restrict__ bv, float* __restrict__ dst){
  int idx = blockIdx.x*256 + threadIdx.x;
  if (idx < NL*QKVW){
    int l = idx / QKVW, c = idx % QKVW;
    float v = (c < 512) ? bq[l*512 + c] : (c < 1024) ? bk[l*512 + c - 512] : bv[l*512 + c - 1024];
    dst[idx] = v;
  }
}

// ================================================================ host
extern "C" void kernel_launch(void* const* d_in, const int* in_sizes, int n_in,
                              void* d_out, int out_size, void* d_ws, size_t ws_size,
                              hipStream_t stream)
{
  const int* inputs = (const int*)d_in[0];
  const int* target = (const int*)d_in[1];
  const float* emb[7];
  for (int i=0;i<7;i++) emb[i] = (const float*)d_in[2+i];
  const float* in_W  = (const float*)d_in[9];
  const float* in_b  = (const float*)d_in[10];
  const float* Wq = (const float*)d_in[11];
  const float* Wk = (const float*)d_in[12];
  const float* Wv = (const float*)d_in[13];
  const float* Wo = (const float*)d_in[14];
  const float* W1 = (const float*)d_in[15];
  const float* W2 = (const float*)d_in[16];
  const float* bq = (const float*)d_in[17];
  const float* bk = (const float*)d_in[18];
  const float* bv = (const float*)d_in[19];
  const float* bo = (const float*)d_in[20];
  const float* b1 = (const float*)d_in[21];
  const float* b2 = (const float*)d_in[22];
  const float* ln1_b = (const float*)d_in[23];
  const float* ln2_b = (const float*)d_in[24];
  const float* norm_b = (const float*)d_in[25];
  const float* catb   = (const float*)d_in[26];
  const float* ln1_g = (const float*)d_in[27];
  const float* ln2_g = (const float*)d_in[28];
  const float* norm_g = (const float*)d_in[29];
  const float* pW[7]; const float* pb[7];
  for (int i=0;i<7;i++){ pW[i]=(const float*)d_in[30+2*i]; pb[i]=(const float*)d_in[31+2*i]; }
  const float* catW = (const float*)d_in[44];
  float* outp = (float*)d_out;

  char* base = (char*)d_ws;
  size_t off = 0;
  auto alloc = [&](size_t bytes)->void*{ void* p = base + off; off += bytes; off = (off + 255) & ~(size_t)255; return p; };

  float* x    = (float*)alloc((size_t)NM*ND*4);
  u16*   xb   = (u16*)  alloc((size_t)NM*ND*2);
  u16*   qkvb = (u16*)  alloc((size_t)NM*QKVW*2);
  float* tb   = (float*)alloc((size_t)NM*ND*4);
  u16*   ab   = (u16*)  alloc((size_t)NM*ND*2);
  u16*   hb   = (u16*)  alloc((size_t)NM*NFF*2);   // aliases: xe[NM,1280], xc[NM,576]+oc[NM,512]
  float* rc   = (float*)alloc((size_t)NS*32*4);
  float* rs   = (float*)alloc((size_t)NS*32*4);
  float* pe   = (float*)alloc(ND*4);
  float* pref = (float*)alloc((size_t)NB*NH*NCH*5120*4);
  u16*  qkvoT = (u16*)  alloc((size_t)NL*4*ND*ND*2);
  u16*  w1T   = (u16*)  alloc((size_t)NFF*ND*2);
  u16*  w2T   = (u16*)  alloc((size_t)ND*NFF*2);
  u16*  inWT  = (u16*)  alloc((size_t)ND*NEP*2);
  u16*  catWT = (u16*)  alloc((size_t)ND*NXC*2);
  u16*  pwcT  = (u16*)  alloc((size_t)384*512*2);
  float* pbc  = (float*)alloc(344*4);
  u16*  ptT   = (u16*)  alloc((size_t)64*512*2);
  float* pbt  = (float*)alloc(4*4);
  float* bqkv = (float*)alloc((size_t)NL*QKVW*4);
  u16*  xeb = hb;
  u16*  xcb = hb;
  u16*  ocb = hb + (size_t)NM*NXC;

  auto gemm = [&](const u16* A, const u16* BT, const float* bias, float* Cf, u16* Cb,
                  int ntile, int N, int K, int ldc, int act){
    dim3 g(ntile, NM/128);
    if (act) k_gemm<1><<<g, 256, 0, stream>>>(A, BT, bias, Cf, Cb, N, K, ldc);
    else     k_gemm<0><<<g, 256, 0, stream>>>(A, BT, bias, Cf, Cb, N, K, ldc);
  };

  // tables + weight prep
  k_tables<<<256, 256, 0, stream>>>(rc, rs, pe);
  k_trans4<<<dim3(16,16,32), 256, 0, stream>>>(Wq, Wk, Wv, Wo, qkvoT);
  k_trans<<<dim3(16,40), 256, 0, stream>>>(in_W, inWT, NE, ND, NEP);
  k_trans<<<dim3(16,18), 256, 0, stream>>>(catW, catWT, 544, ND, NXC);
  k_pack<<<768, 256, 0, stream>>>(pW[0],pW[1],pW[2],pW[3],pW[4],pW[5],pW[6],
                                  pb[0],pb[1],pb[2],pb[3],pb[4],pb[5],pb[6],
                                  pwcT, pbc, ptT, pbt);
  k_bqkv<<<(NL*QKVW+255)/256, 256, 0, stream>>>(bq, bk, bv, bqkv);

  // embedding + input projection + PE
  k_embed<<<NM, 256, 0, stream>>>(inputs, emb[0],emb[1],emb[2],emb[3],emb[4],emb[5],emb[6], xeb);
  gemm(xeb, inWT, in_b, x, nullptr, ND/64, ND, NEP, ND, 0);
  k_addpe<<<NM, 256, 0, stream>>>(x, pe, xb);

  dim3 agrid(NCH, NH, NB);
  for (int l = 0; l < NL; l++){
    k_trans<<<dim3(64,16), 256, 0, stream>>>(W1 + (size_t)l*ND*NFF, w1T, ND, NFF, ND);
    k_trans<<<dim3(16,64), 256, 0, stream>>>(W2 + (size_t)l*NFF*ND, w2T, NFF, ND, NFF);
    // fused QKV GEMM: BT rows = [Wq^T;Wk^T;Wv^T] contiguous in qkvoT
    gemm(xb, qkvoT + (size_t)l*4*ND*ND, bqkv + l*QKVW, nullptr, qkvb, QKVW/64, QKVW, ND, QKVW, 0);
    k_ropephi<<<NM, 256, 0, stream>>>(qkvb, rc, rs);
    k_att1<<<agrid, 256, 0, stream>>>(qkvb, pref);
    k_att2<<<dim3(20,16), 256, 0, stream>>>(pref);
    k_att3<<<agrid, 256, 0, stream>>>(qkvb, pref, ab);
    gemm(ab, qkvoT + (size_t)(l*4+3)*ND*ND, bo + l*ND, tb, nullptr, ND/64, ND, ND, ND, 0);
    k_ln<<<NM, 256, 0, stream>>>(x, tb, x, xb, ln1_g + l*ND, ln1_b + l*ND);
    gemm(xb, w1T, b1 + l*NFF, nullptr, hb, NFF/64, NFF, ND, NFF, 1);
    gemm(hb, w2T, b2 + l*ND, tb, nullptr, ND/64, ND, NFF, ND, 0);
    k_ln<<<NM, 256, 0, stream>>>(x, tb, x, xb, ln2_g + l*ND, ln2_b + l*ND);
  }

  // final LN
  k_ln<<<NM, 256, 0, stream>>>(x, nullptr, x, xb, norm_g, norm_b);

  // heads
  k_xc<<<NM, 256, 0, stream>>>(x, target, emb[3], xcb);
  gemm(xcb, catWT, catb, nullptr, ocb, ND/64, ND, NXC, ND, 0);
  gemm(ocb, pwcT, pbc, outp, nullptr, 6, 343, ND, 343, 0);
  gemm(xb, ptT, pbt, outp + 209, nullptr, 1, 4, ND, 343, 0);
}

// Round 4
// 1141.989 us; speedup vs baseline: 4.1677x; 1.0605x over previous
//
#include <hip/hip_runtime.h>
#include <math.h>

typedef unsigned short u16;
typedef short bf16x8 __attribute__((ext_vector_type(8)));
typedef float f32x4 __attribute__((ext_vector_type(4)));
typedef u16 u16x4 __attribute__((ext_vector_type(4)));
typedef u16 u16x8 __attribute__((ext_vector_type(8)));

#define NB 2
#define NS 2048
#define ND 512
#define NH 8
#define NHD 64
#define NL 8
#define NFF 2048
#define NM (NB*NS)      // 4096 rows
#define NE 1248
#define NEP 1280        // padded K for input proj
#define NXC 576         // padded K for cat proj (544 -> 576)
#define CHK 64
#define NCH (NS/CHK)    // 32 chunks
#define QKVW 1536       // fused qkv row width

__device__ inline float b2f(u16 u){ union{ unsigned int i; float f;} x; x.i = ((unsigned int)u)<<16; return x.f; }
__device__ inline u16 f2b(float f){ union{ float f; unsigned int i;} x; x.f=f; unsigned int r = x.i + 0x7fffu + ((x.i>>16)&1u); return (u16)(r>>16); }

// ---------------------------------------------------------------- tables
__global__ void k_tables(float* rc, float* rs, float* pe){
  int tid = blockIdx.x*blockDim.x + threadIdx.x;
  if (tid < NS*32){
    int s = tid >> 5, j = tid & 31;
    double inv = exp(-(double)(2*j) * log(10000.0) / (double)NHD);
    double ang = (double)s * inv;
    rc[tid] = (float)cos(ang);
    rs[tid] = (float)sin(ang);
  }
  if (tid < ND/2){
    double div = exp(-(double)(2*tid) * log(10000.0) / (double)ND);
    double ang = (double)NS * div;
    pe[2*tid]   = (float)sin(ang);
    pe[2*tid+1] = (float)cos(ang);
  }
}

// ---------------------------------------------------------------- embedding gather+concat (scaled) -> bf16, K padded to 1280
__global__ void k_embed(const int* __restrict__ inp,
    const float* __restrict__ e0, const float* __restrict__ e1, const float* __restrict__ e2,
    const float* __restrict__ e3, const float* __restrict__ e4, const float* __restrict__ e5,
    const float* __restrict__ e6, u16* __restrict__ xe)
{
  int row = blockIdx.x;
  int i0 = inp[row*7+0], i1 = inp[row*7+1], i2 = inp[row*7+2], i3 = inp[row*7+3],
      i4 = inp[row*7+4], i5 = inp[row*7+5], i6 = inp[row*7+6];
  size_t base = (size_t)row*NEP;
  for (int c = threadIdx.x; c < NEP; c += 256){
    float val = 0.f;
    if      (c < 128)  val = e0[i0*128 + c]        * 11.3137084990f;
    else if (c < 384)  val = e1[i1*256 + (c-128)]  * 16.0f;
    else if (c < 448)  val = e2[i2*64  + (c-384)]  * 8.0f;
    else if (c < 480)  val = e3[i3*32  + (c-448)]  * 5.6568542495f;
    else if (c < 992)  val = e4[i4*512 + (c-480)]  * 22.6274169980f;
    else if (c < 1120) val = e5[i5*128 + (c-992)]  * 11.3137084990f;
    else if (c < NE)   val = e6[i6*128 + (c-1120)] * 11.3137084990f;
    xe[base + c] = f2b(val);
  }
}

// ---------------------------------------------------------------- fp32 [K][N] -> bf16 [N][Kpad] transpose/convert (zero pad k>=K)
__device__ inline void trans_tile(const float* __restrict__ W, u16* __restrict__ WT,
                                  int K, int N, int Kpad, int bx, int by){
  __shared__ float t[32][33];
  int tx = threadIdx.x & 31, ty = threadIdx.x >> 5;
  int k0 = by*32, n0 = bx*32;
  #pragma unroll
  for (int i=0;i<4;i++){
    int k = k0 + ty + i*8, n = n0 + tx;
    t[ty+i*8][tx] = (k<K && n<N) ? W[(size_t)k*N + n] : 0.f;
  }
  __syncthreads();
  #pragma unroll
  for (int i=0;i<4;i++){
    int n = n0 + ty + i*8, k = k0 + tx;
    if (n<N && k<Kpad) WT[(size_t)n*Kpad + k] = f2b(t[tx][ty+i*8]);
  }
}
__global__ void k_trans(const float* __restrict__ W, u16* __restrict__ WT, int K, int N, int Kpad){
  trans_tile(W, WT, K, N, Kpad, blockIdx.x, blockIdx.y);
}
__global__ void k_trans4(const float* __restrict__ Wq, const float* __restrict__ Wk,
                         const float* __restrict__ Wv, const float* __restrict__ Wo,
                         u16* __restrict__ dst){
  int z = blockIdx.z, l = z>>2, s = z&3;
  const float* W = (s==0?Wq:s==1?Wk:s==2?Wv:Wo) + (size_t)l*ND*ND;
  trans_tile(W, dst + (size_t)z*ND*ND, ND, ND, ND, blockIdx.x, blockIdx.y);
}
// per-layer W1 [512,2048] and W2 [2048,512] in one launch (2048 blocks)
__global__ void k_transw(const float* __restrict__ W1l, const float* __restrict__ W2l,
                         u16* __restrict__ w1T, u16* __restrict__ w2T){
  int bid = blockIdx.x;
  if (bid < 1024) trans_tile(W1l, w1T, ND, NFF, ND, bid & 63, bid >> 6);
  else { bid -= 1024; trans_tile(W2l, w2T, NFF, ND, NFF, bid & 15, bid >> 4); }
}

// ---------------------------------------------------------------- bf16 MFMA GEMM
// 128x64 tile, BK=64, double-buffered LDS, xor-swizzled staging (pre-swizzled
// global source since global_load_lds writes linearly), split-K capable.
// A: [.][lda] bf16 ; BT: [Npad][ldb] bf16 ; C += bias only when bias!=null.
template<int ACT>
__global__ __launch_bounds__(256) void k_gemm(
    const u16* __restrict__ A, const u16* __restrict__ BT,
    const float* __restrict__ bias, float* __restrict__ Cf, u16* __restrict__ Cb,
    int N, int klen, int lda, int ldb, int ldc)
{
  __shared__ u16 As[2][128*64];
  __shared__ u16 Bs[2][64*64];
  int tid = threadIdx.x;
  int w = tid >> 6, lane = tid & 63;
  int m0 = blockIdx.y*128, n0 = blockIdx.x*64;
  f32x4 acc[4][2];
  #pragma unroll
  for (int m=0;m<4;m++)
    #pragma unroll
    for (int n=0;n<2;n++) acc[m][n] = (f32x4){0.f,0.f,0.f,0.f};

  int lg = lane>>3;                 // row within 8-row staging group
  int cg = (lane&7) ^ lg;           // pre-swizzled source chunk (16B granules)
  const u16* ag = A  + (size_t)(m0 + w*32 + lg)*lda + cg*8;
  const u16* bg = BT + (size_t)(n0 + w*16 + lg)*ldb + cg*8;
  int wrow = (w>>1)*64, wcol = (w&1)*32;
  int lr = lane & 15;
  int rx = lr & 7;                  // read-side row xor
  int cb_ = lane >> 4;              // fragment k-granule base

  auto STAGE = [&](int buf, int k0){
    #pragma unroll
    for (int i=0;i<4;i++)
      __builtin_amdgcn_global_load_lds(
        (__attribute__((address_space(1))) void*)(void*)(ag + (size_t)(i*8)*lda + k0),
        (__attribute__((address_space(3))) void*)(&As[buf][(w*32 + i*8)*64]), 16, 0, 0);
    #pragma unroll
    for (int j=0;j<2;j++)
      __builtin_amdgcn_global_load_lds(
        (__attribute__((address_space(1))) void*)(void*)(bg + (size_t)(j*8)*ldb + k0),
        (__attribute__((address_space(3))) void*)(&Bs[buf][(w*16 + j*8)*64]), 16, 0, 0);
  };

  int nk = klen >> 6;
  STAGE(0, 0);
  __syncthreads();
  for (int t = 0; t < nk; ++t){
    int cur = t & 1;
    // ds_read all fragments for this K-step (swizzled granule)
    bf16x8 af[2][4], bfr[2][2];
    #pragma unroll
    for (int kk=0;kk<2;kk++){
      int gA = ((kk*4 + cb_) ^ rx) * 8;
      #pragma unroll
      for (int m=0;m<4;m++) af[kk][m] = *(const bf16x8*)&As[cur][(wrow + m*16 + lr)*64 + gA];
      #pragma unroll
      for (int n=0;n<2;n++) bfr[kk][n] = *(const bf16x8*)&Bs[cur][(wcol + n*16 + lr)*64 + gA];
    }
    if (t+1 < nk) STAGE(cur^1, (t+1) << 6);
    #pragma unroll
    for (int kk=0;kk<2;kk++)
      #pragma unroll
      for (int m=0;m<4;m++)
        #pragma unroll
        for (int n=0;n<2;n++)
          acc[m][n] = __builtin_amdgcn_mfma_f32_16x16x32_bf16(af[kk][m], bfr[kk][n], acc[m][n], 0,0,0);
    __syncthreads();
  }
  #pragma unroll
  for (int n=0;n<2;n++){
    int col = n0 + wcol + n*16 + lr;
    if (col < N){
      float bv = bias ? bias[col] : 0.f;
      #pragma unroll
      for (int m=0;m<4;m++){
        #pragma unroll
        for (int r=0;r<4;r++){
          int row = m0 + wrow + m*16 + (lane>>4)*4 + r;
          float v = acc[m][n][r] + bv;
          if (ACT==1) v = 0.5f*v*(1.f+erff(v*0.70710678118654752f));
          if (Cf) Cf[(size_t)row*ldc + col] = v;
          if (Cb) Cb[(size_t)row*ldc + col] = f2b(v);
        }
      }
    }
  }
}

// ---------------------------------------------------------------- x += pe ; xb = bf16(x)
__global__ void k_addpe(float* __restrict__ x, const float* __restrict__ pe, u16* __restrict__ xb){
  int row = blockIdx.x, tid = threadIdx.x;
  size_t b = (size_t)row*ND;
  float v0 = x[b+tid] + pe[tid];
  float v1 = x[b+tid+256] + pe[tid+256];
  x[b+tid]=v0; x[b+tid+256]=v1;
  xb[b+tid]=f2b(v0); xb[b+tid+256]=f2b(v1);
}

// ---------------------------------------------------------------- RoPE + phi (elu+1) on fused qkv buffer (q and k sections)
__global__ void k_ropephi(u16* __restrict__ qkv, const float* __restrict__ rc, const float* __restrict__ rs){
  int idx = blockIdx.x*256 + threadIdx.x;
  int row = idx >> 8;
  int p = idx & 255;
  int h = p >> 5, j = p & 31;
  int s = row & (NS-1);
  float cc = rc[s*32+j], sn = rs[s*32+j];
  size_t i1 = (size_t)row*QKVW + h*NHD + j, i2 = i1 + 32;
  float q1=b2f(qkv[i1]), q2=b2f(qkv[i2]);
  float r1 = q1*cc - q2*sn, r2 = q2*cc + q1*sn;
  qkv[i1] = f2b((r1 > 0.f) ? r1+1.f : expf(r1));
  qkv[i2] = f2b((r2 > 0.f) ? r2+1.f : expf(r2));
  float k1=b2f(qkv[i1+512]), k2=b2f(qkv[i2+512]);
  r1 = k1*cc - k2*sn; r2 = k2*cc + k1*sn;
  qkv[i1+512] = f2b((r1 > 0.f) ? r1+1.f : expf(r1));
  qkv[i2+512] = f2b((r2 > 0.f) ? r2+1.f : expf(r2));
}

// ---------------------------------------------------------------- att1: per-chunk [V^T;1]·K -> pref tile [80][64] = [ckv^T ; cks]
__global__ __launch_bounds__(256) void k_att1(const u16* __restrict__ qkv, float* __restrict__ pref){
  int c = blockIdx.x, h = blockIdx.y, b = blockIdx.z;
  __shared__ u16 Kt[64*64];   // [m][t] xor-swizzled
  __shared__ u16 Vt[80*64];   // [d_ext][t] xor-swizzled; row64=ones, 65-79=0
  int tid = threadIdx.x;
  {
    int t = tid & 63, dseg = (tid>>6)*16;
    const u16* kg = qkv + ((size_t)(b*NS + c*CHK + t))*QKVW + 512 + h*NHD + dseg;
    u16x8 k0 = *(const u16x8*)kg;
    u16x8 k1 = *(const u16x8*)(kg+8);
    u16x8 v0 = *(const u16x8*)(kg+512);
    u16x8 v1 = *(const u16x8*)(kg+520);
    #pragma unroll
    for (int e=0;e<8;e++){
      int d0 = dseg+e, d1 = dseg+8+e;
      Kt[(d0*64+t) ^ ((d0&7)<<3)] = k0[e];
      Kt[(d1*64+t) ^ ((d1&7)<<3)] = k1[e];
      Vt[(d0*64+t) ^ ((d0&7)<<3)] = v0[e];
      Vt[(d1*64+t) ^ ((d1&7)<<3)] = v1[e];
    }
    if (tid < 64) Vt[4096 + tid] = 0x3F80;   // ones row (row 64, swz=0)
    for (int e = tid; e < 15*64; e += 256){
      int r = 65 + (e>>6), tt = e&63;
      Vt[(r*64+tt) ^ ((r&7)<<3)] = 0;
    }
  }
  __syncthreads();
  int lane = tid & 63, w = tid >> 6;
  int lr = lane & 15, lk = (lane>>4)*8;
  f32x4 acc[5];
  #pragma unroll
  for (int i=0;i<5;i++) acc[i] = (f32x4){0.f,0.f,0.f,0.f};
  #pragma unroll
  for (int kk=0;kk<2;kk++){
    int mcol = w*16 + lr;
    bf16x8 bfrag = *(const bf16x8*)&Kt[(mcol*64 + kk*32 + lk) ^ ((mcol&7)<<3)];
    #pragma unroll
    for (int fr=0; fr<5; fr++){
      int arow = fr*16 + lr;
      bf16x8 afrag = *(const bf16x8*)&Vt[(arow*64 + kk*32 + lk) ^ ((arow&7)<<3)];
      acc[fr] = __builtin_amdgcn_mfma_f32_16x16x32_bf16(afrag, bfrag, acc[fr], 0,0,0);
    }
  }
  size_t base = (((size_t)(b*NH + h))*NCH + c)*5120;
  int g = lane>>4;
  #pragma unroll
  for (int fr=0; fr<5; fr++)
    #pragma unroll
    for (int r=0;r<4;r++)
      pref[base + (fr*16 + g*4 + r)*64 + w*16 + lr] = acc[fr][r];
}

// ---------------------------------------------------------------- att2: exclusive prefix over 32 chunks, register-pipelined
__global__ __launch_bounds__(256) void k_att2(float* __restrict__ pref){
  int bh = blockIdx.y;
  int e = blockIdx.x*256 + threadIdx.x;   // 0..5119
  size_t base = (size_t)bh*NCH*5120 + e;
  float v[NCH];
  #pragma unroll
  for (int c=0;c<NCH;c++) v[c] = pref[base + (size_t)c*5120];
  float run = 0.f;
  #pragma unroll
  for (int c=0;c<NCH;c++){ float t = v[c]; pref[base + (size_t)c*5120] = run; run += t; }
}

// ---------------------------------------------------------------- att3: MFMA in-chunk attention
// S^T = K·Q^T (masked), O = S·[V|1] + Q·[pkv^T|pks]; col 64 = denominator
__global__ __launch_bounds__(256) void k_att3(const u16* __restrict__ qkv,
    const float* __restrict__ pref, u16* __restrict__ outa)
{
  int c = blockIdx.x, h = blockIdx.y, b = blockIdx.z;
  __shared__ u16 Qs[4096], Ks[4096], Sm[4096];   // [row][64] xor-swz
  __shared__ u16 Vt[5120], Ps[5120];             // [80][64] xor-swz
  __shared__ float dens[64];
  int tid = threadIdx.x;
  {
    int row = tid>>2, seg = (tid&3)*16;
    const u16* qg = qkv + ((size_t)(b*NS + c*CHK + row))*QKVW + h*NHD + seg;
    u16x8 q0 = *(const u16x8*)qg;
    u16x8 q1 = *(const u16x8*)(qg+8);
    u16x8 kk0 = *(const u16x8*)(qg+512);
    u16x8 kk1 = *(const u16x8*)(qg+520);
    int sw = (row&7)<<3;
    *(u16x8*)&Qs[(row*64+seg) ^ sw]     = q0;
    *(u16x8*)&Qs[(row*64+seg+8) ^ sw]   = q1;
    *(u16x8*)&Ks[(row*64+seg) ^ sw]     = kk0;
    *(u16x8*)&Ks[(row*64+seg+8) ^ sw]   = kk1;
  }
  {
    int t = tid&63, dseg = (tid>>6)*16;
    const u16* vg = qkv + ((size_t)(b*NS + c*CHK + t))*QKVW + 1024 + h*NHD + dseg;
    u16x8 v0 = *(const u16x8*)vg;
    u16x8 v1 = *(const u16x8*)(vg+8);
    #pragma unroll
    for (int e=0;e<8;e++){
      int d0=dseg+e, d1=dseg+8+e;
      Vt[(d0*64+t)^((d0&7)<<3)] = v0[e];
      Vt[(d1*64+t)^((d1&7)<<3)] = v1[e];
    }
    if (tid<64) Vt[4096+tid] = 0x3F80;
    for (int e=tid; e<15*64; e+=256){
      int r = 65+(e>>6), tt = e&63;
      Vt[(r*64+tt)^((r&7)<<3)] = 0;
    }
  }
  {
    size_t pb = (((size_t)(b*NH + h))*NCH + c)*5120;
    for (int e=tid; e<5120; e+=256){
      int row = e>>6, m = e&63;
      Ps[(row*64+m)^((row&7)<<3)] = f2b(pref[pb+e]);
    }
  }
  __syncthreads();
  int lane = tid&63, w = tid>>6;
  int lr = lane&15, lk = (lane>>4)*8, g = lane>>4;
  // phase A: S^T[t][i] for this wave's i-strip
  f32x4 sacc[4];
  #pragma unroll
  for (int i=0;i<4;i++) sacc[i] = (f32x4){0.f,0.f,0.f,0.f};
  int iq = w*16 + lr;
  #pragma unroll
  for (int kk=0;kk<2;kk++){
    bf16x8 bq = *(const bf16x8*)&Qs[(iq*64 + kk*32 + lk) ^ ((iq&7)<<3)];
    #pragma unroll
    for (int ft=0; ft<4; ft++){
      int tr = ft*16 + lr;
      bf16x8 ak = *(const bf16x8*)&Ks[(tr*64 + kk*32 + lk) ^ ((tr&7)<<3)];
      sacc[ft] = __builtin_amdgcn_mfma_f32_16x16x32_bf16(ak, bq, sacc[ft], 0,0,0);
    }
  }
  // masked write S[i][t] (b64 per fragment)
  #pragma unroll
  for (int ft=0; ft<4; ft++){
    int t0 = ft*16 + g*4;
    u16x4 pk;
    #pragma unroll
    for (int r=0;r<4;r++) pk[r] = f2b((t0+r <= iq) ? sacc[ft][r] : 0.f);
    *(u16x4*)&Sm[(iq*64 + t0) ^ ((iq&7)<<3)] = pk;
  }
  __syncthreads();
  // phase B: O[i][col] = S·[V|1] + Q·[pkv^T|pks]
  f32x4 acc[5];
  #pragma unroll
  for (int i=0;i<5;i++) acc[i] = (f32x4){0.f,0.f,0.f,0.f};
  #pragma unroll
  for (int kk=0;kk<2;kk++){
    int sw = (iq&7)<<3;
    bf16x8 as = *(const bf16x8*)&Sm[(iq*64 + kk*32 + lk) ^ sw];
    bf16x8 aq = *(const bf16x8*)&Qs[(iq*64 + kk*32 + lk) ^ sw];
    #pragma unroll
    for (int c5=0;c5<5;c5++){
      int col = c5*16 + lr, sw2 = (col&7)<<3;
      bf16x8 bv = *(const bf16x8*)&Vt[(col*64 + kk*32 + lk) ^ sw2];
      bf16x8 bp = *(const bf16x8*)&Ps[(col*64 + kk*32 + lk) ^ sw2];
      acc[c5] = __builtin_amdgcn_mfma_f32_16x16x32_bf16(as, bv, acc[c5], 0,0,0);
      acc[c5] = __builtin_amdgcn_mfma_f32_16x16x32_bf16(aq, bp, acc[c5], 0,0,0);
    }
  }
  if (lr == 0){
    #pragma unroll
    for (int r=0;r<4;r++) dens[w*16 + g*4 + r] = acc[4][r];
  }
  __syncthreads();
  #pragma unroll
  for (int c5=0;c5<4;c5++){
    #pragma unroll
    for (int r=0;r<4;r++){
      int i = w*16 + g*4 + r;
      float z = 1.f/(dens[i] + 1e-6f);
      outa[((size_t)(b*NS + c*CHK + i))*ND + h*NHD + c5*16 + lr] = f2b(acc[c5][r]*z);
    }
  }
}

// ---------------------------------------------------------------- layernorm with up to two residual partials
__global__ __launch_bounds__(256) void k_ln(const float* __restrict__ xin, const float* __restrict__ res,
    const float* __restrict__ res2, float* __restrict__ outx, u16* __restrict__ outb,
    const float* __restrict__ g, const float* __restrict__ bvec)
{
  int row = blockIdx.x, tid = threadIdx.x;
  size_t base = (size_t)row*ND;
  float v0 = xin[base+tid], v1 = xin[base+tid+256];
  if (res){ v0 += res[base+tid]; v1 += res[base+tid+256]; }
  if (res2){ v0 += res2[base+tid]; v1 += res2[base+tid+256]; }
  float s = v0+v1, ss2 = v0*v0 + v1*v1;
  #pragma unroll
  for (int o = 32; o >= 1; o >>= 1){
    s   += __shfl_down(s, o, 64);
    ss2 += __shfl_down(ss2, o, 64);
  }
  __shared__ float red[8];
  int wv = tid >> 6, ln = tid & 63;
  if (ln == 0){ red[wv] = s; red[4+wv] = ss2; }
  __syncthreads();
  float stot  = red[0]+red[1]+red[2]+red[3];
  float sstot = red[4]+red[5]+red[6]+red[7];
  float mean = stot * (1.0f/ND);
  float var  = sstot * (1.0f/ND) - mean*mean;
  float inv = 1.0f / sqrtf(var + 1e-5f);
  float o0 = (v0-mean)*inv*g[tid]     + bvec[tid];
  float o1 = (v1-mean)*inv*g[tid+256] + bvec[tid+256];
  outx[base+tid] = o0; outx[base+tid+256] = o1;
  if (outb){ outb[base+tid] = f2b(o0); outb[base+tid+256] = f2b(o1); }
}

// ---------------------------------------------------------------- build xc = [x | emb_type(target)*sqrt(32) | pad] bf16, K=576
__global__ void k_xc(const float* __restrict__ x, const int* __restrict__ tgt,
                     const float* __restrict__ embt, u16* __restrict__ xc){
  int row = blockIdx.x;
  int id = tgt[row*7+3];
  size_t base = (size_t)row*NXC;
  for (int c = threadIdx.x; c < NXC; c += 256){
    float v = (c < ND) ? x[(size_t)row*ND + c]
            : (c < 544 ? embt[id*32 + (c-ND)]*5.6568542495f : 0.f);
    xc[base + c] = f2b(v);
  }
}

// ---------------------------------------------------------------- pack head weights transposed+pre-scaled
__global__ void k_pack(const float* p0,const float* p1,const float* p2,const float* p3,
                       const float* p4,const float* p5,const float* p6,
                       const float* q0,const float* q1,const float* q2,const float* q3,
                       const float* q4,const float* q5,const float* q6,
                       u16* __restrict__ pwcT, float* __restrict__ pbc,
                       u16* __restrict__ ptT, float* __restrict__ pbt){
  int idx = blockIdx.x*256 + threadIdx.x;   // 384*512
  const int off[8] = {0,56,191,209,213,300,318,343};
  int col = idx >> 9, k = idx & 511;
  if (col < 384){
    u16 v = 0;
    if (col < 343){
      int f = 0;
      while (col >= off[f+1]) f++;
      int cc = col - off[f];
      int V = off[f+1]-off[f];
      const float* P = (f==0)?p0:(f==1)?p1:(f==2)?p2:(f==3)?p3:(f==4)?p4:(f==5)?p5:p6;
      v = f2b(P[(size_t)k*V + cc] * sqrtf((float)V));
    }
    pwcT[(size_t)col*512 + k] = v;
  }
  if (idx < 64*512){
    int n = idx >> 9;
    ptT[idx] = (n < 4) ? f2b(p3[(size_t)k*4 + n]*2.0f) : (u16)0;
  }
  if (idx < 343){
    int c2 = idx, f = 0;
    while (c2 >= off[f+1]) f++;
    int cc = c2 - off[f]; int V = off[f+1]-off[f];
    const float* Q = (f==0)?q0:(f==1)?q1:(f==2)?q2:(f==3)?q3:(f==4)?q4:(f==5)?q5:q6;
    pbc[idx] = Q[cc]*sqrtf((float)V);
  }
  if (idx < 4) pbt[idx] = q3[idx]*2.0f;
}

// ---------------------------------------------------------------- pack fused qkv bias
__global__ void k_bqkv(const float* __restrict__ bq, const float* __restrict__ bk,
                       const float* __restrict__ bv, float* __restrict__ dst){
  int idx = blockIdx.x*256 + threadIdx.x;
  if (idx < NL*QKVW){
    int l = idx / QKVW, c = idx % QKVW;
    float v = (c < 512) ? bq[l*512 + c] : (c < 1024) ? bk[l*512 + c - 512] : bv[l*512 + c - 1024];
    dst[idx] = v;
  }
}

// ================================================================ host
extern "C" void kernel_launch(void* const* d_in, const int* in_sizes, int n_in,
                              void* d_out, int out_size, void* d_ws, size_t ws_size,
                              hipStream_t stream)
{
  const int* inputs = (const int*)d_in[0];
  const int* target = (const int*)d_in[1];
  const float* emb[7];
  for (int i=0;i<7;i++) emb[i] = (const float*)d_in[2+i];
  const float* in_W  = (const float*)d_in[9];
  const float* in_b  = (const float*)d_in[10];
  const float* Wq = (const float*)d_in[11];
  const float* Wk = (const float*)d_in[12];
  const float* Wv = (const float*)d_in[13];
  const float* Wo = (const float*)d_in[14];
  const float* W1 = (const float*)d_in[15];
  const float* W2 = (const float*)d_in[16];
  const float* bq = (const float*)d_in[17];
  const float* bk = (const float*)d_in[18];
  const float* bv = (const float*)d_in[19];
  const float* bo = (const float*)d_in[20];
  const float* b1 = (const float*)d_in[21];
  const float* b2 = (const float*)d_in[22];
  const float* ln1_b = (const float*)d_in[23];
  const float* ln2_b = (const float*)d_in[24];
  const float* norm_b = (const float*)d_in[25];
  const float* catb   = (const float*)d_in[26];
  const float* ln1_g = (const float*)d_in[27];
  const float* ln2_g = (const float*)d_in[28];
  const float* norm_g = (const float*)d_in[29];
  const float* pW[7]; const float* pb[7];
  for (int i=0;i<7;i++){ pW[i]=(const float*)d_in[30+2*i]; pb[i]=(const float*)d_in[31+2*i]; }
  const float* catW = (const float*)d_in[44];
  float* outp = (float*)d_out;

  char* base = (char*)d_ws;
  size_t off = 0;
  auto alloc = [&](size_t bytes)->void*{ void* p = base + off; off += bytes; off = (off + 255) & ~(size_t)255; return p; };

  float* x    = (float*)alloc((size_t)NM*ND*4);
  u16*   xb   = (u16*)  alloc((size_t)NM*ND*2);
  u16*   qkvb = (u16*)  alloc((size_t)NM*QKVW*2);
  float* tb   = (float*)alloc((size_t)NM*ND*4);
  float* tb2  = (float*)alloc((size_t)NM*ND*4);
  u16*   ab   = (u16*)  alloc((size_t)NM*ND*2);
  u16*   hb   = (u16*)  alloc((size_t)NM*NFF*2);   // aliases: xe[NM,1280], xc[NM,576]+oc[NM,512]
  float* rc   = (float*)alloc((size_t)NS*32*4);
  float* rs   = (float*)alloc((size_t)NS*32*4);
  float* pe   = (float*)alloc(ND*4);
  float* pref = (float*)alloc((size_t)NB*NH*NCH*5120*4);
  u16*  qkvoT = (u16*)  alloc((size_t)NL*4*ND*ND*2);
  u16*  w1T   = (u16*)  alloc((size_t)NFF*ND*2);
  u16*  w2T   = (u16*)  alloc((size_t)ND*NFF*2);
  u16*  inWT  = (u16*)  alloc((size_t)ND*NEP*2);
  u16*  catWT = (u16*)  alloc((size_t)ND*NXC*2);
  u16*  pwcT  = (u16*)  alloc((size_t)384*512*2);
  float* pbc  = (float*)alloc(344*4);
  u16*  ptT   = (u16*)  alloc((size_t)64*512*2);
  float* pbt  = (float*)alloc(4*4);
  float* bqkv = (float*)alloc((size_t)NL*QKVW*4);
  u16*  xeb = hb;
  u16*  xcb = hb;
  u16*  ocb = hb + (size_t)NM*NXC;

  auto gemm = [&](const u16* A, const u16* BT, const float* bias, float* Cf, u16* Cb,
                  int ntile, int N, int klen, int lda, int ldb, int ldc, int act){
    dim3 g(ntile, NM/128);
    if (act) k_gemm<1><<<g, 256, 0, stream>>>(A, BT, bias, Cf, Cb, N, klen, lda, ldb, ldc);
    else     k_gemm<0><<<g, 256, 0, stream>>>(A, BT, bias, Cf, Cb, N, klen, lda, ldb, ldc);
  };

  // tables + weight prep
  k_tables<<<256, 256, 0, stream>>>(rc, rs, pe);
  k_trans4<<<dim3(16,16,32), 256, 0, stream>>>(Wq, Wk, Wv, Wo, qkvoT);
  k_trans<<<dim3(16,40), 256, 0, stream>>>(in_W, inWT, NE, ND, NEP);
  k_trans<<<dim3(16,18), 256, 0, stream>>>(catW, catWT, 544, ND, NXC);
  k_pack<<<768, 256, 0, stream>>>(pW[0],pW[1],pW[2],pW[3],pW[4],pW[5],pW[6],
                                  pb[0],pb[1],pb[2],pb[3],pb[4],pb[5],pb[6],
                                  pwcT, pbc, ptT, pbt);
  k_bqkv<<<(NL*QKVW+255)/256, 256, 0, stream>>>(bq, bk, bv, bqkv);

  // embedding + input projection + PE
  k_embed<<<NM, 256, 0, stream>>>(inputs, emb[0],emb[1],emb[2],emb[3],emb[4],emb[5],emb[6], xeb);
  gemm(xeb, inWT, in_b, x, nullptr, ND/64, ND, NEP, NEP, NEP, ND, 0);
  k_addpe<<<NM, 256, 0, stream>>>(x, pe, xb);

  dim3 agrid(NCH, NH, NB);
  for (int l = 0; l < NL; l++){
    k_transw<<<2048, 256, 0, stream>>>(W1 + (size_t)l*ND*NFF, W2 + (size_t)l*NFF*ND, w1T, w2T);
    const u16* woT = qkvoT + (size_t)(l*4+3)*ND*ND;
    // fused QKV GEMM
    gemm(xb, qkvoT + (size_t)l*4*ND*ND, bqkv + l*QKVW, nullptr, qkvb, QKVW/64, QKVW, ND, ND, ND, QKVW, 0);
    k_ropephi<<<NM, 256, 0, stream>>>(qkvb, rc, rs);
    k_att1<<<agrid, 256, 0, stream>>>(qkvb, pref);
    k_att2<<<dim3(20,16), 256, 0, stream>>>(pref);
    k_att3<<<agrid, 256, 0, stream>>>(qkvb, pref, ab);
    // Wo split-K=2
    gemm(ab,      woT,      bo + l*ND, tb,  nullptr, ND/64, ND, 256, ND, ND, ND, 0);
    gemm(ab+256,  woT+256,  nullptr,   tb2, nullptr, ND/64, ND, 256, ND, ND, ND, 0);
    k_ln<<<NM, 256, 0, stream>>>(x, tb, tb2, x, xb, ln1_g + l*ND, ln1_b + l*ND);
    gemm(xb, w1T, b1 + l*NFF, nullptr, hb, NFF/64, NFF, ND, ND, ND, NFF, 1);
    // W2 split-K=2
    gemm(hb,       w2T,       b2 + l*ND, tb,  nullptr, ND/64, ND, 1024, NFF, NFF, ND, 0);
    gemm(hb+1024,  w2T+1024,  nullptr,   tb2, nullptr, ND/64, ND, 1024, NFF, NFF, ND, 0);
    k_ln<<<NM, 256, 0, stream>>>(x, tb, tb2, x, xb, ln2_g + l*ND, ln2_b + l*ND);
  }

  // final LN
  k_ln<<<NM, 256, 0, stream>>>(x, nullptr, nullptr, x, xb, norm_g, norm_b);

  // heads
  k_xc<<<NM, 256, 0, stream>>>(x, target, emb[3], xcb);
  gemm(xcb, catWT, catb, nullptr, ocb, ND/64, ND, NXC, NXC, NXC, ND, 0);
  gemm(ocb, pwcT, pbc, outp, nullptr, 6, 343, ND, ND, ND, 343, 0);
  gemm(xb, ptT, pbt, outp + 209, nullptr, 1, 4, ND, ND, ND, 343, 0);
}